// Round 1
// baseline (738.478 us; speedup 1.0000x reference)
//
#include <hip/hip_runtime.h>
#include <math.h>

#define B 8
#define C 256
#define L 2046
#define LP 2048
#define IC 64
#define DQ 8
#define OC 128
#define BN_EPS 1e-5f

// workspace layout (float offsets)
#define OFF_A     0            // y1 / feat1 (in-place BN) / y51 / sa_conv
#define OFF_B     1048576      // y2 / feat2 / y52 / sc_conv
#define OFF_V     2097152      // v
#define OFF_SAF   3145728      // sa_feat
#define OFF_SCF   4194304      // sc_feat
#define OFF_Q     5242880
#define OFF_K     5373952
#define OFF_E     5505024      // CAM energy 8*64*64
#define OFF_ATTN  5537792
#define OFF_STATS 5570560      // 4 slots * 64ch * 2

__global__ void k_zero(float* __restrict__ energy, float* __restrict__ out_sasc) {
    int i = blockIdx.x * 256 + threadIdx.x;
    if (i < B * IC * IC) energy[i] = 0.f;
    if (i < B * OC) out_sasc[i] = 0.f;
}

// y1 = W5a*x, y2 = W5c*x, written into padded [B,64,2048] with zero pad cols
__global__ __launch_bounds__(256) void k_convx(const float* __restrict__ x,
        const float* __restrict__ W5a, const float* __restrict__ W5c,
        float* __restrict__ y1, float* __restrict__ y2) {
    int l = blockIdx.x * 256 + threadIdx.x;   // 0..2047, guard < L
    int og = blockIdx.y;                      // 16 groups of 4 outputs
    int b = blockIdx.z;
    float a1[4] = {0,0,0,0}, a2[4] = {0,0,0,0};
    if (l < L) {
        const float* xb = x + (size_t)b * C * L + l;
        for (int c = 0; c < C; ++c) {
            float xv = xb[(size_t)c * L];
#pragma unroll
            for (int oo = 0; oo < 4; ++oo) {
                int o = og * 4 + oo;
                a1[oo] = fmaf(W5a[o * C + c], xv, a1[oo]);
                a2[oo] = fmaf(W5c[o * C + c], xv, a2[oo]);
            }
        }
    }
#pragma unroll
    for (int oo = 0; oo < 4; ++oo) {
        size_t row = ((size_t)b * IC + og * 4 + oo) * LP;
        if (l < L) { y1[row + l + 1] = a1[oo]; y2[row + l + 1] = a2[oo]; }
        if (l == 0) {
            y1[row] = 0.f; y1[row + LP - 1] = 0.f;
            y2[row] = 0.f; y2[row + LP - 1] = 0.f;
        }
    }
}

// per-channel sum & sumsq over B*LP
__global__ void k_stats(const float* __restrict__ y, float* __restrict__ stats) {
    int ch = blockIdx.x;
    float s = 0.f, s2 = 0.f;
    for (int i = threadIdx.x; i < B * LP; i += 256) {
        int b = i >> 11, l = i & (LP - 1);
        float v = y[((size_t)b * IC + ch) * LP + l];
        s += v; s2 += v * v;
    }
    for (int off = 32; off; off >>= 1) {
        s += __shfl_down(s, off, 64);
        s2 += __shfl_down(s2, off, 64);
    }
    __shared__ float rs[4], rs2[4];
    int w = threadIdx.x >> 6;
    if ((threadIdx.x & 63) == 0) { rs[w] = s; rs2[w] = s2; }
    __syncthreads();
    if (threadIdx.x == 0) {
        s = rs[0] + rs[1] + rs[2] + rs[3];
        s2 = rs2[0] + rs2[1] + rs2[2] + rs2[3];
        stats[ch * 2] = s; stats[ch * 2 + 1] = s2;
    }
}

// in-place BN(train) + ReLU
__global__ void k_bnrelu(float* __restrict__ y, const float* __restrict__ stats,
                         const float* __restrict__ g, const float* __restrict__ beta) {
    int idx = blockIdx.x * 256 + threadIdx.x;
    int ch = (blockIdx.x >> 3) & (IC - 1);   // 8 blocks per (b,ch) row
    const float invN = 1.f / (float)(B * LP);
    float mu = stats[ch * 2] * invN;
    float var = stats[ch * 2 + 1] * invN - mu * mu;
    float inv = rsqrtf(var + BN_EPS);
    float A = g[ch] * inv;
    float Bc = beta[ch] - mu * A;
    float v = fmaf(A, y[idx], Bc);
    y[idx] = v > 0.f ? v : 0.f;
}

// q,k,v projections from feat1
__global__ __launch_bounds__(256) void k_qkv(const float* __restrict__ f1,
        const float* __restrict__ Wq, const float* __restrict__ bq,
        const float* __restrict__ Wk, const float* __restrict__ bk,
        const float* __restrict__ Wv, const float* __restrict__ bv,
        float* __restrict__ q, float* __restrict__ k, float* __restrict__ v) {
    int l = blockIdx.x * 256 + threadIdx.x;  // 0..2047
    int og = blockIdx.y;                     // 0..19, 4 outputs each
    int b = blockIdx.z;
    const float* fb = f1 + (size_t)b * IC * LP + l;
    int o0 = og * 4;
    const float* W; const float* bias; float* dst;
    if (o0 < 8)       { W = Wq + (size_t)o0 * IC;        bias = bq + o0;        dst = q + ((size_t)b * DQ + o0) * LP; }
    else if (o0 < 16) { W = Wk + (size_t)(o0 - 8) * IC;  bias = bk + (o0 - 8);  dst = k + ((size_t)b * DQ + (o0 - 8)) * LP; }
    else              { W = Wv + (size_t)(o0 - 16) * IC; bias = bv + (o0 - 16); dst = v + ((size_t)b * IC + (o0 - 16)) * LP; }
    float acc[4];
#pragma unroll
    for (int oo = 0; oo < 4; ++oo) acc[oo] = bias[oo];
    for (int c = 0; c < IC; ++c) {
        float fv = fb[(size_t)c * LP];
#pragma unroll
        for (int oo = 0; oo < 4; ++oo) acc[oo] = fmaf(W[oo * IC + c], fv, acc[oo]);
    }
#pragma unroll
    for (int oo = 0; oo < 4; ++oo) dst[(size_t)oo * LP + l] = acc[oo];
}

// flash-style PAM: out[c,l] = sum_m softmax_m(q_l . k_m) v[c,m]; saf = gamma*out + f1
__global__ __launch_bounds__(256) void k_pam(const float* __restrict__ q,
        const float* __restrict__ kk, const float* __restrict__ v,
        const float* __restrict__ f1, const float* __restrict__ gamma,
        float* __restrict__ saf) {
    __shared__ __align__(16) float qs[DQ][64];
    __shared__ __align__(16) float ks[DQ][64];
    __shared__ __align__(16) float vs[64][64];
    __shared__ __align__(16) float ps[64][65];
    __shared__ float redm[64][4], reds[64][4], mi[64], li[64];
    int b = blockIdx.y;
    int l0 = blockIdx.x * 64;
    int lq = threadIdx.x & 63, cg = threadIdx.x >> 6;
    for (int t = threadIdx.x; t < DQ * 64; t += 256) {
        int d = t >> 6, j = t & 63;
        qs[d][j] = q[((size_t)b * DQ + d) * LP + l0 + j];
    }
    if (threadIdx.x < 64) { mi[threadIdx.x] = -INFINITY; li[threadIdx.x] = 0.f; }
    float O[16];
#pragma unroll
    for (int i = 0; i < 16; ++i) O[i] = 0.f;
    __syncthreads();
    float qr[DQ];
#pragma unroll
    for (int d = 0; d < DQ; ++d) qr[d] = qs[d][lq];

    for (int m0 = 0; m0 < LP; m0 += 64) {
        __syncthreads();  // previous tile fully consumed
        for (int t = threadIdx.x; t < DQ * 64; t += 256) {
            int d = t >> 6, j = t & 63;
            ks[d][j] = kk[((size_t)b * DQ + d) * LP + m0 + j];
        }
        for (int t = threadIdx.x; t < 64 * 64; t += 256) {
            int c = t >> 6, j = t & 63;
            vs[c][j] = v[((size_t)b * IC + c) * LP + m0 + j];
        }
        __syncthreads();
        float s[16];
        float lmax = -INFINITY;
#pragma unroll
        for (int jj = 0; jj < 16; ++jj) {
            int j = cg * 16 + jj;
            float e = 0.f;
#pragma unroll
            for (int d = 0; d < DQ; ++d) e = fmaf(qr[d], ks[d][j], e);
            s[jj] = e;
            lmax = fmaxf(lmax, e);
        }
        redm[lq][cg] = lmax;
        __syncthreads();
        float rm = fmaxf(fmaxf(redm[lq][0], redm[lq][1]), fmaxf(redm[lq][2], redm[lq][3]));
        float mold = mi[lq];
        float mnew = fmaxf(mold, rm);
        float alpha = __expf(mold - mnew);
        float lsum = 0.f;
#pragma unroll
        for (int jj = 0; jj < 16; ++jj) {
            float p = __expf(s[jj] - mnew);
            ps[lq][cg * 16 + jj] = p;
            lsum += p;
        }
        reds[lq][cg] = lsum;
#pragma unroll
        for (int i = 0; i < 16; ++i) O[i] *= alpha;
        __syncthreads();
        if (cg == 0) {
            float rsum = reds[lq][0] + reds[lq][1] + reds[lq][2] + reds[lq][3];
            mi[lq] = mnew;
            li[lq] = li[lq] * alpha + rsum;
        }
        // PV: O[c] += sum_j p[j] * vs[c][j]
        for (int j4 = 0; j4 < 16; ++j4) {
            float p0 = ps[lq][4 * j4 + 0];
            float p1 = ps[lq][4 * j4 + 1];
            float p2 = ps[lq][4 * j4 + 2];
            float p3 = ps[lq][4 * j4 + 3];
#pragma unroll
            for (int cc = 0; cc < 16; ++cc) {
                const float4 vv = *reinterpret_cast<const float4*>(&vs[cg * 16 + cc][4 * j4]);
                O[cc] = fmaf(p0, vv.x, fmaf(p1, vv.y, fmaf(p2, vv.z, fmaf(p3, vv.w, O[cc]))));
            }
        }
    }
    __syncthreads();
    float inv = 1.f / li[lq];
    float gm = gamma[0];
#pragma unroll
    for (int cc = 0; cc < 16; ++cc) {
        int c = cg * 16 + cc;
        size_t idx = ((size_t)b * IC + c) * LP + l0 + lq;
        saf[idx] = fmaf(gm, O[cc] * inv, f1[idx]);
    }
}

// CAM Gram: energy[b,c,d] += sum over l-chunk of f[c,l]*f[d,l]
__global__ __launch_bounds__(256) void k_gram(const float* __restrict__ f, float* __restrict__ energy) {
    __shared__ __align__(16) float fs[64][260];
    int b = blockIdx.y;
    int l0 = blockIdx.x * 256;
    for (int t = threadIdx.x; t < 64 * 256; t += 256) {
        int c = t >> 8, i = t & 255;
        fs[c][i] = f[((size_t)b * IC + c) * LP + l0 + i];
    }
    __syncthreads();
    int c = threadIdx.x >> 2, dg = threadIdx.x & 3;
    float acc[16];
#pragma unroll
    for (int i = 0; i < 16; ++i) acc[i] = 0.f;
    for (int i4 = 0; i4 < 64; ++i4) {
        const float4 fc = *reinterpret_cast<const float4*>(&fs[c][i4 * 4]);
#pragma unroll
        for (int dd = 0; dd < 16; ++dd) {
            const float4 fd = *reinterpret_cast<const float4*>(&fs[dg * 16 + dd][i4 * 4]);
            acc[dd] += fc.x * fd.x + fc.y * fd.y + fc.z * fd.z + fc.w * fd.w;
        }
    }
    for (int dd = 0; dd < 16; ++dd)
        atomicAdd(&energy[(size_t)b * IC * IC + c * IC + dg * 16 + dd], acc[dd]);
}

// attn[c,d] = softmax_d(rowmax - energy)
__global__ void k_cam_softmax(const float* __restrict__ energy, float* __restrict__ attn) {
    int b = blockIdx.x, c = threadIdx.x;  // 64 threads
    const float* e = energy + (size_t)b * IC * IC + c * IC;
    float* a = attn + (size_t)b * IC * IC + c * IC;
    float mn = INFINITY;
    for (int d = 0; d < IC; ++d) mn = fminf(mn, e[d]);
    float s = 0.f;
    for (int d = 0; d < IC; ++d) { float p = __expf(mn - e[d]); a[d] = p; s += p; }
    float inv = 1.f / s;
    for (int d = 0; d < IC; ++d) a[d] *= inv;
}

// scf[c,l] = gamma * sum_d attn[c,d]*f[d,l] + f[c,l]
__global__ __launch_bounds__(256) void k_cam_apply(const float* __restrict__ attn,
        const float* __restrict__ f, const float* __restrict__ gamma,
        float* __restrict__ scf) {
    __shared__ __align__(16) float as[64][64];
    int b = blockIdx.y;
    int l = blockIdx.x * 128 + (threadIdx.x & 127);
    int ch = threadIdx.x >> 7;  // 0..1 -> c half
    for (int t = threadIdx.x; t < 64 * 64; t += 256)
        as[t >> 6][t & 63] = attn[(size_t)b * IC * IC + t];
    __syncthreads();
    float acc[32];
#pragma unroll
    for (int i = 0; i < 32; ++i) acc[i] = 0.f;
    const float* fb = f + (size_t)b * IC * LP + l;
    for (int d4 = 0; d4 < 16; ++d4) {
        float f0 = fb[(size_t)(4 * d4 + 0) * LP];
        float f1v = fb[(size_t)(4 * d4 + 1) * LP];
        float f2v = fb[(size_t)(4 * d4 + 2) * LP];
        float f3v = fb[(size_t)(4 * d4 + 3) * LP];
#pragma unroll
        for (int cc = 0; cc < 32; ++cc) {
            const float4 a4 = *reinterpret_cast<const float4*>(&as[ch * 32 + cc][d4 * 4]);
            acc[cc] += a4.x * f0 + a4.y * f1v + a4.z * f2v + a4.w * f3v;
        }
    }
    float gm = gamma[0];
    for (int cc = 0; cc < 32; ++cc) {
        int cidx = ch * 32 + cc;
        size_t idx = ((size_t)b * IC + cidx) * LP + l;
        scf[idx] = fmaf(gm, acc[cc], fb[(size_t)cidx * LP]);
    }
}

// conv k=3 pad=1 over [B,64,2048]
__global__ __launch_bounds__(256) void k_conv3(const float* __restrict__ f,
        const float* __restrict__ W, float* __restrict__ y) {
    int l = blockIdx.x * 256 + threadIdx.x;  // 0..2047
    int og = blockIdx.y;                     // 8 groups of 8 outputs
    int b = blockIdx.z;
    const float* fb = f + (size_t)b * IC * LP;
    float acc[8];
#pragma unroll
    for (int i = 0; i < 8; ++i) acc[i] = 0.f;
    for (int c = 0; c < IC; ++c) {
        const float* fr = fb + (size_t)c * LP;
        float fm = (l > 0) ? fr[l - 1] : 0.f;
        float f0 = fr[l];
        float fp = (l < LP - 1) ? fr[l + 1] : 0.f;
#pragma unroll
        for (int oo = 0; oo < 8; ++oo) {
            const float* w = W + ((size_t)(og * 8 + oo) * IC + c) * 3;
            acc[oo] = fmaf(w[0], fm, fmaf(w[1], f0, fmaf(w[2], fp, acc[oo])));
        }
    }
#pragma unroll
    for (int oo = 0; oo < 8; ++oo)
        y[((size_t)b * IC + og * 8 + oo) * LP + l] = acc[oo];
}

// final 3 conv1x1 + mean over L for sasc
__global__ __launch_bounds__(256) void k_final(const float* __restrict__ sa,
        const float* __restrict__ sc,
        const float* __restrict__ W6, const float* __restrict__ b6,
        const float* __restrict__ W7, const float* __restrict__ b7,
        const float* __restrict__ W8, const float* __restrict__ b8,
        float* __restrict__ out_sasc, float* __restrict__ out_sa,
        float* __restrict__ out_sc) {
    int l = blockIdx.x * 256 + threadIdx.x;  // 0..2047
    int og = blockIdx.y;                     // 32 groups of 4 outputs
    int b = blockIdx.z;
    const float* sab = sa + (size_t)b * IC * LP + l;
    const float* scb = sc + (size_t)b * IC * LP + l;
    float a1[4] = {0,0,0,0}, a2[4] = {0,0,0,0}, a3[4] = {0,0,0,0};
    for (int c = 0; c < IC; ++c) {
        float sv = sab[(size_t)c * LP];
        float cv = scb[(size_t)c * LP];
        float tv = sv + cv;
#pragma unroll
        for (int oo = 0; oo < 4; ++oo) {
            int o = og * 4 + oo;
            a1[oo] = fmaf(W6[o * IC + c], sv, a1[oo]);
            a2[oo] = fmaf(W7[o * IC + c], cv, a2[oo]);
            a3[oo] = fmaf(W8[o * IC + c], tv, a3[oo]);
        }
    }
    __shared__ float red[4][4];
    int wv = threadIdx.x >> 6;
#pragma unroll
    for (int oo = 0; oo < 4; ++oo) {
        int o = og * 4 + oo;
        out_sa[((size_t)b * OC + o) * LP + l] = a1[oo] + b6[o];
        out_sc[((size_t)b * OC + o) * LP + l] = a2[oo] + b7[o];
        float v3 = a3[oo] + b8[o];
        for (int off = 32; off; off >>= 1) v3 += __shfl_down(v3, off, 64);
        if ((threadIdx.x & 63) == 0) red[wv][oo] = v3;
    }
    __syncthreads();
    if (threadIdx.x < 4) {
        float v = red[0][threadIdx.x] + red[1][threadIdx.x] + red[2][threadIdx.x] + red[3][threadIdx.x];
        atomicAdd(&out_sasc[b * OC + og * 4 + threadIdx.x], v * (1.f / (float)LP));
    }
}

extern "C" void kernel_launch(void* const* d_in, const int* in_sizes, int n_in,
                              void* d_out, int out_size, void* d_ws, size_t ws_size,
                              hipStream_t stream) {
    (void)in_sizes; (void)n_in; (void)out_size; (void)ws_size;
    const float* x    = (const float*)d_in[0];
    const float* W5a  = (const float*)d_in[1];
    const float* g5a  = (const float*)d_in[2];
    const float* b5a  = (const float*)d_in[3];
    const float* W5c  = (const float*)d_in[4];
    const float* g5c  = (const float*)d_in[5];
    const float* b5c  = (const float*)d_in[6];
    const float* Wq   = (const float*)d_in[7];
    const float* bq   = (const float*)d_in[8];
    const float* Wk   = (const float*)d_in[9];
    const float* bk   = (const float*)d_in[10];
    const float* Wv   = (const float*)d_in[11];
    const float* bv   = (const float*)d_in[12];
    const float* gpam = (const float*)d_in[13];
    const float* gcam = (const float*)d_in[14];
    const float* W51  = (const float*)d_in[15];
    const float* g51  = (const float*)d_in[16];
    const float* b51  = (const float*)d_in[17];
    const float* W52  = (const float*)d_in[18];
    const float* g52  = (const float*)d_in[19];
    const float* b52  = (const float*)d_in[20];
    const float* W6   = (const float*)d_in[21];
    const float* b6   = (const float*)d_in[22];
    const float* W7   = (const float*)d_in[23];
    const float* b7   = (const float*)d_in[24];
    const float* W8   = (const float*)d_in[25];
    const float* b8   = (const float*)d_in[26];

    float* ws = (float*)d_ws;
    float* out = (float*)d_out;
    float* bufA  = ws + OFF_A;
    float* bufB  = ws + OFF_B;
    float* V     = ws + OFF_V;
    float* SAF   = ws + OFF_SAF;
    float* SCF   = ws + OFF_SCF;
    float* Q     = ws + OFF_Q;
    float* K     = ws + OFF_K;
    float* E     = ws + OFF_E;
    float* ATTN  = ws + OFF_ATTN;
    float* STATS = ws + OFF_STATS;
    float* out_sa = out + B * OC;
    float* out_sc = out + B * OC + (size_t)B * OC * LP;

    k_zero<<<128, 256, 0, stream>>>(E, out);
    k_convx<<<dim3(8, 16, B), 256, 0, stream>>>(x, W5a, W5c, bufA, bufB);
    k_stats<<<64, 256, 0, stream>>>(bufA, STATS);
    k_stats<<<64, 256, 0, stream>>>(bufB, STATS + 128);
    k_bnrelu<<<4096, 256, 0, stream>>>(bufA, STATS, g5a, b5a);
    k_bnrelu<<<4096, 256, 0, stream>>>(bufB, STATS + 128, g5c, b5c);
    k_qkv<<<dim3(8, 20, B), 256, 0, stream>>>(bufA, Wq, bq, Wk, bk, Wv, bv, Q, K, V);
    k_pam<<<dim3(32, B), 256, 0, stream>>>(Q, K, V, bufA, gpam, SAF);
    k_gram<<<dim3(8, B), 256, 0, stream>>>(bufB, E);
    k_cam_softmax<<<B, 64, 0, stream>>>(E, ATTN);
    k_cam_apply<<<dim3(16, B), 256, 0, stream>>>(ATTN, bufB, gcam, SCF);
    k_conv3<<<dim3(8, 8, B), 256, 0, stream>>>(SAF, W51, bufA);
    k_conv3<<<dim3(8, 8, B), 256, 0, stream>>>(SCF, W52, bufB);
    k_stats<<<64, 256, 0, stream>>>(bufA, STATS + 256);
    k_stats<<<64, 256, 0, stream>>>(bufB, STATS + 384);
    k_bnrelu<<<4096, 256, 0, stream>>>(bufA, STATS + 256, g51, b51);
    k_bnrelu<<<4096, 256, 0, stream>>>(bufB, STATS + 384, g52, b52);
    k_final<<<dim3(8, 32, B), 256, 0, stream>>>(bufA, bufB, W6, b6, W7, b7, W8, b8,
                                                out, out_sa, out_sc);
}

// Round 2
// 455.778 us; speedup vs baseline: 1.6203x; 1.6203x over previous
//
#include <hip/hip_runtime.h>
#include <math.h>

#define B 8
#define C 256
#define L 2046
#define LP 2048
#define IC 64
#define DQ 8
#define OC 128
#define BN_EPS 1e-5f

// workspace layout (float offsets)
#define OFF_A     0            // y1 / feat1 (in-place BN) / y51 / sa_conv
#define OFF_B     1048576      // y2 / feat2 / y52 / sc_conv
#define OFF_SAF   2097152      // sa_feat
#define OFF_SCF   3145728      // sc_feat
#define OFF_VB    4194304      // v bf16 [B][IC][LP]
#define OFF_QT    4718592      // qT bf16 [B][LP][8]
#define OFF_KT    4784128      // kT bf16 [B][LP][8]
#define OFF_E     4849664      // CAM energy 8*64*64
#define OFF_ATTN  4882432
#define OFF_STATS 4915200      // 4 slots * 64ch * 2

typedef __attribute__((ext_vector_type(8))) short bshort8;
typedef __attribute__((ext_vector_type(4))) float f32x4;

__device__ __forceinline__ unsigned short f2bf(float f) {
    union { float f; unsigned int u; } v; v.f = f;
    unsigned int r = v.u + 0x7fffu + ((v.u >> 16) & 1u);
    return (unsigned short)(r >> 16);
}

__global__ void k_zero(float* __restrict__ energy, float* __restrict__ out_sasc) {
    int i = blockIdx.x * 256 + threadIdx.x;
    if (i < B * IC * IC) energy[i] = 0.f;
    if (i < B * OC) out_sasc[i] = 0.f;
}

// y1 = W5a*x, y2 = W5c*x, written into padded [B,64,2048] with zero pad cols
__global__ __launch_bounds__(256) void k_convx(const float* __restrict__ x,
        const float* __restrict__ W5a, const float* __restrict__ W5c,
        float* __restrict__ y1, float* __restrict__ y2) {
    int l = blockIdx.x * 256 + threadIdx.x;   // 0..2047, guard < L
    int og = blockIdx.y;                      // 16 groups of 4 outputs
    int b = blockIdx.z;
    float a1[4] = {0,0,0,0}, a2[4] = {0,0,0,0};
    if (l < L) {
        const float* xb = x + (size_t)b * C * L + l;
        for (int c = 0; c < C; ++c) {
            float xv = xb[(size_t)c * L];
#pragma unroll
            for (int oo = 0; oo < 4; ++oo) {
                int o = og * 4 + oo;
                a1[oo] = fmaf(W5a[o * C + c], xv, a1[oo]);
                a2[oo] = fmaf(W5c[o * C + c], xv, a2[oo]);
            }
        }
    }
#pragma unroll
    for (int oo = 0; oo < 4; ++oo) {
        size_t row = ((size_t)b * IC + og * 4 + oo) * LP;
        if (l < L) { y1[row + l + 1] = a1[oo]; y2[row + l + 1] = a2[oo]; }
        if (l == 0) {
            y1[row] = 0.f; y1[row + LP - 1] = 0.f;
            y2[row] = 0.f; y2[row + LP - 1] = 0.f;
        }
    }
}

// per-channel sum & sumsq over B*LP
__global__ void k_stats(const float* __restrict__ y, float* __restrict__ stats) {
    int ch = blockIdx.x;
    float s = 0.f, s2 = 0.f;
    for (int i = threadIdx.x; i < B * LP; i += 256) {
        int b = i >> 11, l = i & (LP - 1);
        float v = y[((size_t)b * IC + ch) * LP + l];
        s += v; s2 += v * v;
    }
    for (int off = 32; off; off >>= 1) {
        s += __shfl_down(s, off, 64);
        s2 += __shfl_down(s2, off, 64);
    }
    __shared__ float rs[4], rs2[4];
    int w = threadIdx.x >> 6;
    if ((threadIdx.x & 63) == 0) { rs[w] = s; rs2[w] = s2; }
    __syncthreads();
    if (threadIdx.x == 0) {
        s = rs[0] + rs[1] + rs[2] + rs[3];
        s2 = rs2[0] + rs2[1] + rs2[2] + rs2[3];
        stats[ch * 2] = s; stats[ch * 2 + 1] = s2;
    }
}

// in-place BN(train) + ReLU
__global__ void k_bnrelu(float* __restrict__ y, const float* __restrict__ stats,
                         const float* __restrict__ g, const float* __restrict__ beta) {
    int idx = blockIdx.x * 256 + threadIdx.x;
    int ch = (blockIdx.x >> 3) & (IC - 1);   // 8 blocks per (b,ch) row
    const float invN = 1.f / (float)(B * LP);
    float mu = stats[ch * 2] * invN;
    float var = stats[ch * 2 + 1] * invN - mu * mu;
    float inv = rsqrtf(var + BN_EPS);
    float A = g[ch] * inv;
    float Bc = beta[ch] - mu * A;
    float v = fmaf(A, y[idx], Bc);
    y[idx] = v > 0.f ? v : 0.f;
}

// q,k,v projections from feat1 -> bf16 buffers (qT/kT l-major, v channel-major)
__global__ __launch_bounds__(256) void k_qkv(const float* __restrict__ f1,
        const float* __restrict__ Wq, const float* __restrict__ bq,
        const float* __restrict__ Wk, const float* __restrict__ bk,
        const float* __restrict__ Wv, const float* __restrict__ bv,
        unsigned short* __restrict__ qT, unsigned short* __restrict__ kT,
        unsigned short* __restrict__ vb) {
    int l = blockIdx.x * 256 + threadIdx.x;  // 0..2047
    int og = blockIdx.y;                     // 0..19, 4 outputs each
    int b = blockIdx.z;
    const float* fb = f1 + (size_t)b * IC * LP + l;
    int o0 = og * 4;
    const float* W; const float* bias;
    if (o0 < 8)       { W = Wq + (size_t)o0 * IC;        bias = bq + o0; }
    else if (o0 < 16) { W = Wk + (size_t)(o0 - 8) * IC;  bias = bk + (o0 - 8); }
    else              { W = Wv + (size_t)(o0 - 16) * IC; bias = bv + (o0 - 16); }
    float acc[4];
#pragma unroll
    for (int oo = 0; oo < 4; ++oo) acc[oo] = bias[oo];
    for (int c = 0; c < IC; ++c) {
        float fv = fb[(size_t)c * LP];
#pragma unroll
        for (int oo = 0; oo < 4; ++oo) acc[oo] = fmaf(W[oo * IC + c], fv, acc[oo]);
    }
    if (o0 < 8) {
#pragma unroll
        for (int oo = 0; oo < 4; ++oo)
            qT[((size_t)(b * LP + l)) * 8 + o0 + oo] = f2bf(acc[oo]);
    } else if (o0 < 16) {
#pragma unroll
        for (int oo = 0; oo < 4; ++oo)
            kT[((size_t)(b * LP + l)) * 8 + (o0 - 8) + oo] = f2bf(acc[oo]);
    } else {
#pragma unroll
        for (int oo = 0; oo < 4; ++oo)
            vb[((size_t)(b * IC + (o0 - 16) + oo)) * LP + l] = f2bf(acc[oo]);
    }
}

// flash-style PAM via MFMA bf16.
// Per block: 64 queries (4 waves x 16), loop over key tiles of 64.
// QK: A[q][d] (K padded 8->32 with zeros), B[d][key]. PV: A[q][key], B[key][c].
__global__ __launch_bounds__(256) void k_pam_mfma(
        const unsigned short* __restrict__ qT, const unsigned short* __restrict__ kT,
        const unsigned short* __restrict__ vb, const float* __restrict__ f1,
        const float* __restrict__ gamma, float* __restrict__ saf) {
    __shared__ unsigned short vs[64 * 72];       // v tile [c][key], stride 72 (2-way free)
    __shared__ unsigned short ps[4 * 16 * 72];   // per-wave P tile [q][key]
    __shared__ float os[64 * 65];                // output transpose buffer
    int b = blockIdx.y;
    int l0 = blockIdx.x * 64;
    int tid = threadIdx.x;
    int wq = tid >> 6;           // wave id -> query subtile
    int lane = tid & 63;
    int n = lane & 15, quad = lane >> 4;

    // Q fragment: A[m=lane&15][k=quad*8+j]; only quad 0 (d=0..7) nonzero
    bshort8 qa = {};
    if (quad == 0)
        qa = *(const bshort8*)(qT + ((size_t)(b * LP + l0 + wq * 16 + n)) * 8);

    f32x4 acc[4];
#pragma unroll
    for (int s = 0; s < 4; ++s) acc[s] = (f32x4){0.f, 0.f, 0.f, 0.f};
    float mi[4] = {-INFINITY, -INFINITY, -INFINITY, -INFINITY};
    float li[4] = {0.f, 0.f, 0.f, 0.f};
    unsigned short* pw = ps + wq * 16 * 72;

    for (int m0 = 0; m0 < LP; m0 += 64) {
        __syncthreads();   // prev vs tile fully consumed
        {   // stage v tile: 64 rows x 64 keys bf16
            int row = tid >> 2, ch = tid & 3;
            const unsigned short* src = vb + ((size_t)(b * IC + row)) * LP + m0 + ch * 16;
            unsigned short* dst = vs + row * 72 + ch * 16;
            *(bshort8*)dst = *(const bshort8*)src;
            *(bshort8*)(dst + 8) = *(const bshort8*)(src + 8);
        }
        bshort8 kb[4];
#pragma unroll
        for (int s = 0; s < 4; ++s) kb[s] = (bshort8){};
        if (quad == 0) {
#pragma unroll
            for (int s = 0; s < 4; ++s)
                kb[s] = *(const bshort8*)(kT + ((size_t)(b * LP + m0 + s * 16 + n)) * 8);
        }
        __syncthreads();
        // QK^T: s[sub] D[row=q(local), col=key]
        f32x4 sc[4];
#pragma unroll
        for (int s = 0; s < 4; ++s)
            sc[s] = __builtin_amdgcn_mfma_f32_16x16x32_bf16(qa, kb[s],
                        (f32x4){0.f, 0.f, 0.f, 0.f}, 0, 0, 0);
        // online softmax per row r (row = quad*4+r)
        float alpha[4];
#pragma unroll
        for (int r = 0; r < 4; ++r) {
            float lmax = fmaxf(fmaxf(sc[0][r], sc[1][r]), fmaxf(sc[2][r], sc[3][r]));
#pragma unroll
            for (int msk = 1; msk < 16; msk <<= 1)
                lmax = fmaxf(lmax, __shfl_xor(lmax, msk, 64));
            float mnew = fmaxf(mi[r], lmax);
            alpha[r] = __expf(mi[r] - mnew);
            float rs = 0.f;
#pragma unroll
            for (int s = 0; s < 4; ++s) {
                float pe = __expf(sc[s][r] - mnew);
                pw[(quad * 4 + r) * 72 + s * 16 + n] = f2bf(pe);
                rs += pe;
            }
#pragma unroll
            for (int msk = 1; msk < 16; msk <<= 1)
                rs += __shfl_xor(rs, msk, 64);
            li[r] = li[r] * alpha[r] + rs;
            mi[r] = mnew;
        }
        // rescale accumulators
#pragma unroll
        for (int s = 0; s < 4; ++s)
#pragma unroll
            for (int r = 0; r < 4; ++r) acc[s][r] *= alpha[r];
        // PV: A = P (from own wave's LDS), B = v tile
#pragma unroll
        for (int step = 0; step < 2; ++step) {
            bshort8 pa = *(const bshort8*)(pw + n * 72 + step * 32 + quad * 8);
#pragma unroll
            for (int s = 0; s < 4; ++s) {
                bshort8 vf = *(const bshort8*)(vs + (s * 16 + n) * 72 + step * 32 + quad * 8);
                acc[s] = __builtin_amdgcn_mfma_f32_16x16x32_bf16(pa, vf, acc[s], 0, 0, 0);
            }
        }
    }
    __syncthreads();
    // transpose O through LDS: os[c][q]
#pragma unroll
    for (int s = 0; s < 4; ++s)
#pragma unroll
        for (int r = 0; r < 4; ++r)
            os[(s * 16 + n) * 65 + wq * 16 + quad * 4 + r] = acc[s][r] / li[r];
    __syncthreads();
    float gm = gamma[0];
    int c = tid >> 2, qc = tid & 3;
    size_t base = ((size_t)(b * IC + c)) * LP + l0 + qc * 16;
#pragma unroll
    for (int i = 0; i < 16; i += 4) {
        float4 fv = *(const float4*)(f1 + base + i);
        float4 ov;
        ov.x = fmaf(gm, os[c * 65 + qc * 16 + i + 0], fv.x);
        ov.y = fmaf(gm, os[c * 65 + qc * 16 + i + 1], fv.y);
        ov.z = fmaf(gm, os[c * 65 + qc * 16 + i + 2], fv.z);
        ov.w = fmaf(gm, os[c * 65 + qc * 16 + i + 3], fv.w);
        *(float4*)(saf + base + i) = ov;
    }
}

// CAM Gram: energy[b,c,d] += sum over l-chunk of f[c,l]*f[d,l]
__global__ __launch_bounds__(256) void k_gram(const float* __restrict__ f, float* __restrict__ energy) {
    __shared__ __align__(16) float fs[64][260];
    int b = blockIdx.y;
    int l0 = blockIdx.x * 256;
    for (int t = threadIdx.x; t < 64 * 256; t += 256) {
        int c = t >> 8, i = t & 255;
        fs[c][i] = f[((size_t)b * IC + c) * LP + l0 + i];
    }
    __syncthreads();
    int c = threadIdx.x >> 2, dg = threadIdx.x & 3;
    float acc[16];
#pragma unroll
    for (int i = 0; i < 16; ++i) acc[i] = 0.f;
    for (int i4 = 0; i4 < 64; ++i4) {
        const float4 fc = *reinterpret_cast<const float4*>(&fs[c][i4 * 4]);
#pragma unroll
        for (int dd = 0; dd < 16; ++dd) {
            const float4 fd = *reinterpret_cast<const float4*>(&fs[dg * 16 + dd][i4 * 4]);
            acc[dd] += fc.x * fd.x + fc.y * fd.y + fc.z * fd.z + fc.w * fd.w;
        }
    }
    for (int dd = 0; dd < 16; ++dd)
        atomicAdd(&energy[(size_t)b * IC * IC + c * IC + dg * 16 + dd], acc[dd]);
}

// attn[c,d] = softmax_d(rowmax - energy)
__global__ void k_cam_softmax(const float* __restrict__ energy, float* __restrict__ attn) {
    int b = blockIdx.x, c = threadIdx.x;  // 64 threads
    const float* e = energy + (size_t)b * IC * IC + c * IC;
    float* a = attn + (size_t)b * IC * IC + c * IC;
    float mn = INFINITY;
    for (int d = 0; d < IC; ++d) mn = fminf(mn, e[d]);
    float s = 0.f;
    for (int d = 0; d < IC; ++d) { float p = __expf(mn - e[d]); a[d] = p; s += p; }
    float inv = 1.f / s;
    for (int d = 0; d < IC; ++d) a[d] *= inv;
}

// scf[c,l] = gamma * sum_d attn[c,d]*f[d,l] + f[c,l]
__global__ __launch_bounds__(256) void k_cam_apply(const float* __restrict__ attn,
        const float* __restrict__ f, const float* __restrict__ gamma,
        float* __restrict__ scf) {
    __shared__ __align__(16) float as[64][64];
    int b = blockIdx.y;
    int l = blockIdx.x * 128 + (threadIdx.x & 127);
    int ch = threadIdx.x >> 7;  // 0..1 -> c half
    for (int t = threadIdx.x; t < 64 * 64; t += 256)
        as[t >> 6][t & 63] = attn[(size_t)b * IC * IC + t];
    __syncthreads();
    float acc[32];
#pragma unroll
    for (int i = 0; i < 32; ++i) acc[i] = 0.f;
    const float* fb = f + (size_t)b * IC * LP + l;
    for (int d4 = 0; d4 < 16; ++d4) {
        float f0 = fb[(size_t)(4 * d4 + 0) * LP];
        float f1v = fb[(size_t)(4 * d4 + 1) * LP];
        float f2v = fb[(size_t)(4 * d4 + 2) * LP];
        float f3v = fb[(size_t)(4 * d4 + 3) * LP];
#pragma unroll
        for (int cc = 0; cc < 32; ++cc) {
            const float4 a4 = *reinterpret_cast<const float4*>(&as[ch * 32 + cc][d4 * 4]);
            acc[cc] += a4.x * f0 + a4.y * f1v + a4.z * f2v + a4.w * f3v;
        }
    }
    float gm = gamma[0];
    for (int cc = 0; cc < 32; ++cc) {
        int cidx = ch * 32 + cc;
        size_t idx = ((size_t)b * IC + cidx) * LP + l;
        scf[idx] = fmaf(gm, acc[cc], fb[(size_t)cidx * LP]);
    }
}

// conv k=3 pad=1 over [B,64,2048]
__global__ __launch_bounds__(256) void k_conv3(const float* __restrict__ f,
        const float* __restrict__ W, float* __restrict__ y) {
    int l = blockIdx.x * 256 + threadIdx.x;  // 0..2047
    int og = blockIdx.y;                     // 8 groups of 8 outputs
    int b = blockIdx.z;
    const float* fb = f + (size_t)b * IC * LP;
    float acc[8];
#pragma unroll
    for (int i = 0; i < 8; ++i) acc[i] = 0.f;
    for (int c = 0; c < IC; ++c) {
        const float* fr = fb + (size_t)c * LP;
        float fm = (l > 0) ? fr[l - 1] : 0.f;
        float f0 = fr[l];
        float fp = (l < LP - 1) ? fr[l + 1] : 0.f;
#pragma unroll
        for (int oo = 0; oo < 8; ++oo) {
            const float* w = W + ((size_t)(og * 8 + oo) * IC + c) * 3;
            acc[oo] = fmaf(w[0], fm, fmaf(w[1], f0, fmaf(w[2], fp, acc[oo])));
        }
    }
#pragma unroll
    for (int oo = 0; oo < 8; ++oo)
        y[((size_t)b * IC + og * 8 + oo) * LP + l] = acc[oo];
}

// final 3 conv1x1 + mean over L for sasc
__global__ __launch_bounds__(256) void k_final(const float* __restrict__ sa,
        const float* __restrict__ sc,
        const float* __restrict__ W6, const float* __restrict__ b6,
        const float* __restrict__ W7, const float* __restrict__ b7,
        const float* __restrict__ W8, const float* __restrict__ b8,
        float* __restrict__ out_sasc, float* __restrict__ out_sa,
        float* __restrict__ out_sc) {
    int l = blockIdx.x * 256 + threadIdx.x;  // 0..2047
    int og = blockIdx.y;                     // 32 groups of 4 outputs
    int b = blockIdx.z;
    const float* sab = sa + (size_t)b * IC * LP + l;
    const float* scb = sc + (size_t)b * IC * LP + l;
    float a1[4] = {0,0,0,0}, a2[4] = {0,0,0,0}, a3[4] = {0,0,0,0};
    for (int c = 0; c < IC; ++c) {
        float sv = sab[(size_t)c * LP];
        float cv = scb[(size_t)c * LP];
        float tv = sv + cv;
#pragma unroll
        for (int oo = 0; oo < 4; ++oo) {
            int o = og * 4 + oo;
            a1[oo] = fmaf(W6[o * IC + c], sv, a1[oo]);
            a2[oo] = fmaf(W7[o * IC + c], cv, a2[oo]);
            a3[oo] = fmaf(W8[o * IC + c], tv, a3[oo]);
        }
    }
    __shared__ float red[4][4];
    int wv = threadIdx.x >> 6;
#pragma unroll
    for (int oo = 0; oo < 4; ++oo) {
        int o = og * 4 + oo;
        out_sa[((size_t)b * OC + o) * LP + l] = a1[oo] + b6[o];
        out_sc[((size_t)b * OC + o) * LP + l] = a2[oo] + b7[o];
        float v3 = a3[oo] + b8[o];
        for (int off = 32; off; off >>= 1) v3 += __shfl_down(v3, off, 64);
        if ((threadIdx.x & 63) == 0) red[wv][oo] = v3;
    }
    __syncthreads();
    if (threadIdx.x < 4) {
        float v = red[0][threadIdx.x] + red[1][threadIdx.x] + red[2][threadIdx.x] + red[3][threadIdx.x];
        atomicAdd(&out_sasc[b * OC + og * 4 + threadIdx.x], v * (1.f / (float)LP));
    }
}

extern "C" void kernel_launch(void* const* d_in, const int* in_sizes, int n_in,
                              void* d_out, int out_size, void* d_ws, size_t ws_size,
                              hipStream_t stream) {
    (void)in_sizes; (void)n_in; (void)out_size; (void)ws_size;
    const float* x    = (const float*)d_in[0];
    const float* W5a  = (const float*)d_in[1];
    const float* g5a  = (const float*)d_in[2];
    const float* b5a  = (const float*)d_in[3];
    const float* W5c  = (const float*)d_in[4];
    const float* g5c  = (const float*)d_in[5];
    const float* b5c  = (const float*)d_in[6];
    const float* Wq   = (const float*)d_in[7];
    const float* bq   = (const float*)d_in[8];
    const float* Wk   = (const float*)d_in[9];
    const float* bk   = (const float*)d_in[10];
    const float* Wv   = (const float*)d_in[11];
    const float* bv   = (const float*)d_in[12];
    const float* gpam = (const float*)d_in[13];
    const float* gcam = (const float*)d_in[14];
    const float* W51  = (const float*)d_in[15];
    const float* g51  = (const float*)d_in[16];
    const float* b51  = (const float*)d_in[17];
    const float* W52  = (const float*)d_in[18];
    const float* g52  = (const float*)d_in[19];
    const float* b52  = (const float*)d_in[20];
    const float* W6   = (const float*)d_in[21];
    const float* b6   = (const float*)d_in[22];
    const float* W7   = (const float*)d_in[23];
    const float* b7   = (const float*)d_in[24];
    const float* W8   = (const float*)d_in[25];
    const float* b8   = (const float*)d_in[26];

    float* ws = (float*)d_ws;
    float* out = (float*)d_out;
    float* bufA  = ws + OFF_A;
    float* bufB  = ws + OFF_B;
    float* SAF   = ws + OFF_SAF;
    float* SCF   = ws + OFF_SCF;
    unsigned short* VB = (unsigned short*)(ws + OFF_VB);
    unsigned short* QT = (unsigned short*)(ws + OFF_QT);
    unsigned short* KT = (unsigned short*)(ws + OFF_KT);
    float* E     = ws + OFF_E;
    float* ATTN  = ws + OFF_ATTN;
    float* STATS = ws + OFF_STATS;
    float* out_sa = out + B * OC;
    float* out_sc = out + B * OC + (size_t)B * OC * LP;

    k_zero<<<128, 256, 0, stream>>>(E, out);
    k_convx<<<dim3(8, 16, B), 256, 0, stream>>>(x, W5a, W5c, bufA, bufB);
    k_stats<<<64, 256, 0, stream>>>(bufA, STATS);
    k_stats<<<64, 256, 0, stream>>>(bufB, STATS + 128);
    k_bnrelu<<<4096, 256, 0, stream>>>(bufA, STATS, g5a, b5a);
    k_bnrelu<<<4096, 256, 0, stream>>>(bufB, STATS + 128, g5c, b5c);
    k_qkv<<<dim3(8, 20, B), 256, 0, stream>>>(bufA, Wq, bq, Wk, bk, Wv, bv, QT, KT, VB);
    k_pam_mfma<<<dim3(32, B), 256, 0, stream>>>(QT, KT, VB, bufA, gpam, SAF);
    k_gram<<<dim3(8, B), 256, 0, stream>>>(bufB, E);
    k_cam_softmax<<<B, 64, 0, stream>>>(E, ATTN);
    k_cam_apply<<<dim3(16, B), 256, 0, stream>>>(ATTN, bufB, gcam, SCF);
    k_conv3<<<dim3(8, 8, B), 256, 0, stream>>>(SAF, W51, bufA);
    k_conv3<<<dim3(8, 8, B), 256, 0, stream>>>(SCF, W52, bufB);
    k_stats<<<64, 256, 0, stream>>>(bufA, STATS + 256);
    k_stats<<<64, 256, 0, stream>>>(bufB, STATS + 384);
    k_bnrelu<<<4096, 256, 0, stream>>>(bufA, STATS + 256, g51, b51);
    k_bnrelu<<<4096, 256, 0, stream>>>(bufB, STATS + 384, g52, b52);
    k_final<<<dim3(8, 32, B), 256, 0, stream>>>(bufA, bufB, W6, b6, W7, b7, W8, b8,
                                                out, out_sa, out_sc);
}

// Round 3
// 319.478 us; speedup vs baseline: 2.3115x; 1.4266x over previous
//
#include <hip/hip_runtime.h>
#include <math.h>

#define B 8
#define C 256
#define L 2046
#define LP 2048
#define IC 64
#define OC 128
#define BN_EPS 1e-5f

// ws offsets (float units)
#define OFF_A      0u          // y1 / feat1 (fp32, in-place BN) / y51
#define OFF_B      1048576u    // y2 / feat2 / y52
#define OFF_FT1    2097152u    // feat1^T bf16 [b][l][64]
#define OFF_SAFT   2621440u    // sa_feat^T bf16 [b][l][64]
#define OFF_SCFT   3145728u    // sc_feat^T bf16
#define OFF_SACT   3670016u    // sa_conv^T bf16 (post BN2)
#define OFF_SCCT   4194304u    // sc_conv^T bf16
#define OFF_VB     4718592u    // v bf16 [b][64][l]
#define OFF_QT     5242880u    // q^T bf16 [b][l][8]
#define OFF_KT     5308416u
#define OFF_EPART  5373952u    // CAM gram partials [b][8][64][64]
#define OFF_ATTN   5636096u
#define OFF_STATS  5668864u    // 4 slots * 64ch * 2
#define OFF_MLPART 5669376u    // [b][qt][ks][128]
#define OFF_FSPART 5800448u    // [b][lt][64]
#define OFF_W5BF   5816832u    // bf16 [128][256]
#define OFF_W67    5833216u    // bf16 [2][128][64]
#define OFF_WT     5841408u    // bf16 [2][3][64][64]
#define OFF_WQKV   5853696u    // bf16 [80][64]
#define OFF_BQKV   5856256u    // fp32 [80]

typedef __attribute__((ext_vector_type(8))) short bshort8;
typedef __attribute__((ext_vector_type(4))) float f32x4;

__device__ __forceinline__ unsigned short f2bf(float f) {
    union { float f; unsigned int u; } v; v.f = f;
    unsigned int r = v.u + 0x7fffu + ((v.u >> 16) & 1u);
    return (unsigned short)(r >> 16);
}
__device__ __forceinline__ float bf2f(unsigned short u) {
    union { unsigned int i; float f; } v; v.i = ((unsigned int)u) << 16;
    return v.f;
}

// ---- weight prep: convert/transform all weights to bf16 layouts ----
__global__ __launch_bounds__(256) void k_wprep(
        const float* __restrict__ W5a, const float* __restrict__ W5c,
        const float* __restrict__ W6, const float* __restrict__ W7,
        const float* __restrict__ W51, const float* __restrict__ W52,
        const float* __restrict__ Wq, const float* __restrict__ Wk,
        const float* __restrict__ Wv, const float* __restrict__ bq,
        const float* __restrict__ bk, const float* __restrict__ bv,
        unsigned short* __restrict__ W5BF, unsigned short* __restrict__ W67,
        unsigned short* __restrict__ WT, unsigned short* __restrict__ WQKV,
        float* __restrict__ BQKV) {
    int i = blockIdx.x * 256 + threadIdx.x;
    if (i < 32768) {
        int o = i >> 8, c = i & 255;
        W5BF[i] = f2bf(o < 64 ? W5a[o * 256 + c] : W5c[(o - 64) * 256 + c]);
    } else if (i < 49152) {
        int j = i - 32768; int g = j >> 13; int r = j & 8191;
        W67[j] = f2bf(g ? W7[r] : W6[r]);
    } else if (i < 73728) {
        int j = i - 49152;
        int c = j & 63, o = (j >> 6) & 63, wt = j >> 12; int w = wt / 3, t = wt % 3;
        const float* Ws = w ? W52 : W51;
        WT[j] = f2bf(Ws[(o * 64 + c) * 3 + t]);
    } else if (i < 78848) {
        int j = i - 73728; int o = j >> 6, c = j & 63;
        float v = o < 8 ? Wq[o * 64 + c] : (o < 16 ? Wk[(o - 8) * 64 + c] : Wv[(o - 16) * 64 + c]);
        WQKV[j] = f2bf(v);
    } else if (i < 78928) {
        int o = i - 78848;
        BQKV[o] = o < 8 ? bq[o] : (o < 16 ? bk[o - 8] : bv[o - 16]);
    }
}

// ---- x -> XT bf16 [b][l(2048)][c(256)], rows l>=2046 zeroed ----
__global__ __launch_bounds__(256) void k_xt(const float* __restrict__ x,
        unsigned short* __restrict__ XT) {
    __shared__ unsigned short ts[64 * 66];
    int lt = blockIdx.x, cq = blockIdx.y, b = blockIdx.z;
    int l0 = lt * 64, c0 = cq * 64;
    int t = threadIdx.x, lq = t & 63, cg = t >> 6;
    int l = l0 + lq;
#pragma unroll
    for (int ci = 0; ci < 16; ++ci) {
        int c = c0 + cg * 16 + ci;
        float v = (l < L) ? x[((size_t)b * C + c) * L + l] : 0.f;
        ts[lq * 66 + cg * 16 + ci] = f2bf(v);
    }
    __syncthreads();
    int li = t >> 2, cc = t & 3;
    unsigned int* dst = (unsigned int*)(XT + ((size_t)(b * LP + l0 + li)) * C + c0 + cc * 16);
#pragma unroll
    for (int i = 0; i < 8; ++i)
        dst[i] = *(unsigned int*)(ts + li * 66 + cc * 16 + 2 * i);
}

// ---- conv1x1 (256->64) x2 via MFMA; writes padded [b][64][2048] fp32 ----
__global__ __launch_bounds__(256) void k_convx(const unsigned short* __restrict__ XT,
        const unsigned short* __restrict__ W5BF,
        float* __restrict__ y1, float* __restrict__ y2) {
    int lt = blockIdx.x, og = blockIdx.y, b = blockIdx.z;
    int l0 = lt * 64;
    int w = threadIdx.x >> 6, lane = threadIdx.x & 63;
    int n = lane & 15, quad = lane >> 4;
    int lrow = l0 + w * 16 + n;
    bshort8 xb[8];
#pragma unroll
    for (int kt = 0; kt < 8; ++kt)
        xb[kt] = *(const bshort8*)(XT + ((size_t)(b * LP + lrow)) * C + kt * 32 + quad * 8);
    float* dst = og ? y2 : y1;
    f32x4 acc[4];
#pragma unroll
    for (int ot = 0; ot < 4; ++ot) {
        f32x4 a = {0.f, 0.f, 0.f, 0.f};
#pragma unroll
        for (int kt = 0; kt < 8; ++kt) {
            bshort8 wf = *(const bshort8*)(W5BF + (size_t)(og * 64 + ot * 16 + n) * C + kt * 32 + quad * 8);
            a = __builtin_amdgcn_mfma_f32_16x16x32_bf16(wf, xb[kt], a, 0, 0, 0);
        }
        acc[ot] = a;
    }
#pragma unroll
    for (int ot = 0; ot < 4; ++ot)
#pragma unroll
        for (int r = 0; r < 4; ++r) {
            int o = ot * 16 + quad * 4 + r;
            if (lrow < L) dst[((size_t)(b * IC + o)) * LP + 1 + lrow] = acc[ot][r];
            if (lt == 0 && w == 0 && n == 0) dst[((size_t)(b * IC + o)) * LP] = 0.f;
            if (lt == 31 && w == 3 && n == 15) dst[((size_t)(b * IC + o)) * LP + LP - 1] = 0.f;
        }
}

// ---- per-channel stats for two buffers in one launch ----
__global__ __launch_bounds__(256) void k_stats(const float* __restrict__ yA,
        const float* __restrict__ yB, float* __restrict__ stA, float* __restrict__ stB) {
    int blk = blockIdx.x;
    const float* y = blk < 64 ? yA : yB;
    float* st = blk < 64 ? stA : stB;
    int ch = blk & 63;
    float s = 0.f, s2 = 0.f;
    for (int i = threadIdx.x; i < B * LP; i += 256) {
        int b = i >> 11, l = i & (LP - 1);
        float v = y[((size_t)b * IC + ch) * LP + l];
        s += v; s2 += v * v;
    }
    for (int off = 32; off; off >>= 1) {
        s += __shfl_down(s, off, 64);
        s2 += __shfl_down(s2, off, 64);
    }
    __shared__ float rs[4], rs2[4];
    int w = threadIdx.x >> 6;
    if ((threadIdx.x & 63) == 0) { rs[w] = s; rs2[w] = s2; }
    __syncthreads();
    if (threadIdx.x == 0) {
        st[ch * 2] = rs[0] + rs[1] + rs[2] + rs[3];
        st[ch * 2 + 1] = rs2[0] + rs2[1] + rs2[2] + rs2[3];
    }
}

// ---- stage-1 BN+ReLU: in-place fp32 both buffers, + feat1^T bf16 ----
__global__ __launch_bounds__(256) void k_bnrelu_t1(float* __restrict__ fA,
        float* __restrict__ fB, const float* __restrict__ stats,
        const float* __restrict__ gA, const float* __restrict__ bA,
        const float* __restrict__ gB, const float* __restrict__ bB,
        unsigned short* __restrict__ FT1) {
    __shared__ unsigned short ts[64 * 66];
    int lt = blockIdx.x, b = blockIdx.y;
    int l0 = lt * 64;
    int t = threadIdx.x, lq = t & 63, cg = t >> 6;
    const float invN = 1.f / (float)(B * LP);
#pragma unroll
    for (int ci = 0; ci < 16; ++ci) {
        int c = cg * 16 + ci;
        float mu = stats[c * 2] * invN, va = stats[c * 2 + 1] * invN - mu * mu;
        float Aa = gA[c] * rsqrtf(va + BN_EPS), Ba = bA[c] - mu * Aa;
        float mb = stats[128 + c * 2] * invN, vv = stats[128 + c * 2 + 1] * invN - mb * mb;
        float Ab = gB[c] * rsqrtf(vv + BN_EPS), Bb = bB[c] - mb * Ab;
        size_t idx = ((size_t)(b * IC + c)) * LP + l0 + lq;
        float v1 = fmaf(Aa, fA[idx], Ba); v1 = v1 > 0.f ? v1 : 0.f;
        fA[idx] = v1;
        ts[lq * 66 + c] = f2bf(v1);
        float v2 = fmaf(Ab, fB[idx], Bb); v2 = v2 > 0.f ? v2 : 0.f;
        fB[idx] = v2;
    }
    __syncthreads();
    int li = t >> 2, cc = t & 3;
    unsigned int* dst = (unsigned int*)(FT1 + ((size_t)(b * LP + l0 + li)) * IC + cc * 16);
#pragma unroll
    for (int i = 0; i < 8; ++i)
        dst[i] = *(unsigned int*)(ts + li * 66 + cc * 16 + 2 * i);
}

// ---- qkv projections via MFMA ----
__global__ __launch_bounds__(256) void k_qkv_mfma(const unsigned short* __restrict__ FT1,
        const unsigned short* __restrict__ WQKV, const float* __restrict__ BQKV,
        unsigned short* __restrict__ QT, unsigned short* __restrict__ KT,
        unsigned short* __restrict__ VB) {
    int lt = blockIdx.x, b = blockIdx.y;
    int l0 = lt * 64;
    int w = threadIdx.x >> 6, lane = threadIdx.x & 63, n = lane & 15, quad = lane >> 4;
    int lrow = l0 + w * 16 + n;
    bshort8 fb[2];
#pragma unroll
    for (int kt = 0; kt < 2; ++kt)
        fb[kt] = *(const bshort8*)(FT1 + ((size_t)(b * LP + lrow)) * IC + kt * 32 + quad * 8);
    f32x4 acc[5];
#pragma unroll
    for (int ot = 0; ot < 5; ++ot) {
        f32x4 a = {0.f, 0.f, 0.f, 0.f};
#pragma unroll
        for (int kt = 0; kt < 2; ++kt) {
            bshort8 wf = *(const bshort8*)(WQKV + (size_t)(ot * 16 + n) * IC + kt * 32 + quad * 8);
            a = __builtin_amdgcn_mfma_f32_16x16x32_bf16(wf, fb[kt], a, 0, 0, 0);
        }
        acc[ot] = a;
    }
#pragma unroll
    for (int ot = 0; ot < 5; ++ot)
#pragma unroll
        for (int r = 0; r < 4; ++r) {
            int o = ot * 16 + quad * 4 + r;
            unsigned short bv16 = f2bf(acc[ot][r] + BQKV[o]);
            if (ot == 0) {
                if (o < 8) QT[((size_t)(b * LP + lrow)) * 8 + o] = bv16;
                else KT[((size_t)(b * LP + lrow)) * 8 + (o - 8)] = bv16;
            } else {
                VB[((size_t)(b * IC + (o - 16))) * LP + lrow] = bv16;
            }
        }
}

// ---- flash PAM, split-K over 4 key ranges; writes unnormalized partials ----
__global__ __launch_bounds__(256) void k_pam_mfma(
        const unsigned short* __restrict__ qT, const unsigned short* __restrict__ kT,
        const unsigned short* __restrict__ vb,
        unsigned short* __restrict__ OPART, float* __restrict__ MLPART) {
    __shared__ unsigned char smem[18432];
    unsigned short* vs = (unsigned short*)smem;       // [64][72]
    unsigned short* ps = vs + 4608;                   // 4 x [16][72]
    float* os = (float*)smem;                         // [64][65] (aliased after loop)
    int qt = blockIdx.x, ks = blockIdx.y, b = blockIdx.z;
    int l0 = qt * 64;
    int tid = threadIdx.x;
    int wq = tid >> 6, lane = tid & 63, n = lane & 15, quad = lane >> 4;
    bshort8 qa = {};
    if (quad == 0)
        qa = *(const bshort8*)(qT + ((size_t)(b * LP + l0 + wq * 16 + n)) * 8);
    f32x4 acc[4];
#pragma unroll
    for (int s = 0; s < 4; ++s) acc[s] = (f32x4){0.f, 0.f, 0.f, 0.f};
    float mi[4] = {-INFINITY, -INFINITY, -INFINITY, -INFINITY};
    float li[4] = {0.f, 0.f, 0.f, 0.f};
    unsigned short* pw = ps + wq * 16 * 72;

    for (int it = 0; it < 8; ++it) {
        int m0 = ks * 512 + it * 64;
        __syncthreads();
        {
            int row = tid >> 2, chn = tid & 3;
            const unsigned short* src = vb + ((size_t)(b * IC + row)) * LP + m0 + chn * 16;
            unsigned short* dstl = vs + row * 72 + chn * 16;
            *(bshort8*)dstl = *(const bshort8*)src;
            *(bshort8*)(dstl + 8) = *(const bshort8*)(src + 8);
        }
        bshort8 kb[4];
#pragma unroll
        for (int s = 0; s < 4; ++s) kb[s] = (bshort8){};
        if (quad == 0) {
#pragma unroll
            for (int s = 0; s < 4; ++s)
                kb[s] = *(const bshort8*)(kT + ((size_t)(b * LP + m0 + s * 16 + n)) * 8);
        }
        __syncthreads();
        f32x4 sc[4];
#pragma unroll
        for (int s = 0; s < 4; ++s)
            sc[s] = __builtin_amdgcn_mfma_f32_16x16x32_bf16(qa, kb[s],
                        (f32x4){0.f, 0.f, 0.f, 0.f}, 0, 0, 0);
        float alpha[4];
#pragma unroll
        for (int r = 0; r < 4; ++r) {
            float lmax = fmaxf(fmaxf(sc[0][r], sc[1][r]), fmaxf(sc[2][r], sc[3][r]));
#pragma unroll
            for (int msk = 1; msk < 16; msk <<= 1)
                lmax = fmaxf(lmax, __shfl_xor(lmax, msk, 64));
            float mnew = fmaxf(mi[r], lmax);
            alpha[r] = __expf(mi[r] - mnew);
            float rs = 0.f;
#pragma unroll
            for (int s = 0; s < 4; ++s) {
                float pe = __expf(sc[s][r] - mnew);
                pw[(quad * 4 + r) * 72 + s * 16 + n] = f2bf(pe);
                rs += pe;
            }
#pragma unroll
            for (int msk = 1; msk < 16; msk <<= 1)
                rs += __shfl_xor(rs, msk, 64);
            li[r] = li[r] * alpha[r] + rs;
            mi[r] = mnew;
        }
#pragma unroll
        for (int s = 0; s < 4; ++s)
#pragma unroll
            for (int r = 0; r < 4; ++r) acc[s][r] *= alpha[r];
#pragma unroll
        for (int step = 0; step < 2; ++step) {
            bshort8 pa = *(const bshort8*)(pw + n * 72 + step * 32 + quad * 8);
#pragma unroll
            for (int s = 0; s < 4; ++s) {
                bshort8 vf = *(const bshort8*)(vs + (s * 16 + n) * 72 + step * 32 + quad * 8);
                acc[s] = __builtin_amdgcn_mfma_f32_16x16x32_bf16(pa, vf, acc[s], 0, 0, 0);
            }
        }
    }
    __syncthreads();
#pragma unroll
    for (int s = 0; s < 4; ++s)
#pragma unroll
        for (int r = 0; r < 4; ++r)
            os[(s * 16 + n) * 65 + wq * 16 + quad * 4 + r] = acc[s][r];
    if (n == 0) {
        size_t mlb = ((size_t)((b * 32 + qt) * 4 + ks)) * 128;
#pragma unroll
        for (int r = 0; r < 4; ++r) {
            int q = wq * 16 + quad * 4 + r;
            MLPART[mlb + q] = mi[r];
            MLPART[mlb + 64 + q] = li[r];
        }
    }
    __syncthreads();
    size_t ob = ((size_t)((b * 32 + qt) * 4 + ks)) * 4096;
    int c = tid >> 2, qc = tid & 3;
    unsigned int* od = (unsigned int*)(OPART + ob + c * 64 + qc * 16);
#pragma unroll
    for (int i = 0; i < 8; ++i) {
        unsigned int pk = (unsigned int)f2bf(os[c * 65 + qc * 16 + 2 * i]) |
                          ((unsigned int)f2bf(os[c * 65 + qc * 16 + 2 * i + 1]) << 16);
        od[i] = pk;
    }
}

// ---- merge split-K partials, add residual, write sa_feat^T bf16 ----
__global__ __launch_bounds__(256) void k_pam_combine(
        const unsigned short* __restrict__ OPART, const float* __restrict__ MLPART,
        const float* __restrict__ f1, const float* __restrict__ gamma,
        unsigned short* __restrict__ SAFT) {
    __shared__ float mls[512];
    __shared__ float wv[256];
    __shared__ float dn[64];
    __shared__ unsigned short tile[64 * 66];
    int qt = blockIdx.x, b = blockIdx.y;
    int l0 = qt * 64;
    int t = threadIdx.x;
    size_t mlb = ((size_t)((b * 32 + qt) * 4)) * 128;
    for (int idx = t; idx < 512; idx += 256) mls[idx] = MLPART[mlb + idx];
    __syncthreads();
    if (t < 64) {
        float m0 = mls[t], m1 = mls[128 + t], m2 = mls[256 + t], m3 = mls[384 + t];
        float M = fmaxf(fmaxf(m0, m1), fmaxf(m2, m3));
        float w0 = __expf(m0 - M), w1 = __expf(m1 - M), w2 = __expf(m2 - M), w3 = __expf(m3 - M);
        dn[t] = w0 * mls[64 + t] + w1 * mls[192 + t] + w2 * mls[320 + t] + w3 * mls[448 + t];
        wv[t] = w0; wv[64 + t] = w1; wv[128 + t] = w2; wv[192 + t] = w3;
    }
    __syncthreads();
    int c = t >> 2, qc = t & 3;
    float O[16];
#pragma unroll
    for (int i = 0; i < 16; ++i) O[i] = 0.f;
    size_t ob = ((size_t)((b * 32 + qt) * 4)) * 4096 + c * 64 + qc * 16;
#pragma unroll
    for (int s = 0; s < 4; ++s) {
        bshort8 p0 = *(const bshort8*)(OPART + ob + (size_t)s * 4096);
        bshort8 p1 = *(const bshort8*)(OPART + ob + (size_t)s * 4096 + 8);
#pragma unroll
        for (int i = 0; i < 8; ++i) {
            O[i]     += wv[s * 64 + qc * 16 + i]     * bf2f((unsigned short)p0[i]);
            O[8 + i] += wv[s * 64 + qc * 16 + 8 + i] * bf2f((unsigned short)p1[i]);
        }
    }
    float gm = gamma[0];
#pragma unroll
    for (int i = 0; i < 16; ++i) {
        int q = qc * 16 + i;
        float val = fmaf(gm, O[i] / dn[q], f1[((size_t)(b * IC + c)) * LP + l0 + q]);
        tile[q * 66 + c] = f2bf(val);
    }
    __syncthreads();
    int li = t >> 2, cc = t & 3;
    unsigned int* dst = (unsigned int*)(SAFT + ((size_t)(b * LP + l0 + li)) * IC + cc * 16);
#pragma unroll
    for (int i = 0; i < 8; ++i)
        dst[i] = *(unsigned int*)(tile + li * 66 + cc * 16 + 2 * i);
}

// ---- CAM Gram partials (no atomics) ----
__global__ __launch_bounds__(256) void k_gram(const float* __restrict__ f,
        float* __restrict__ EPART) {
    __shared__ __align__(16) float fs[64][260];
    int b = blockIdx.y;
    int l0 = blockIdx.x * 256;
    for (int t = threadIdx.x; t < 64 * 256; t += 256) {
        int c = t >> 8, i = t & 255;
        fs[c][i] = f[((size_t)b * IC + c) * LP + l0 + i];
    }
    __syncthreads();
    int c = threadIdx.x >> 2, dg = threadIdx.x & 3;
    float acc[16];
#pragma unroll
    for (int i = 0; i < 16; ++i) acc[i] = 0.f;
    for (int i4 = 0; i4 < 64; ++i4) {
        const float4 fc = *reinterpret_cast<const float4*>(&fs[c][i4 * 4]);
#pragma unroll
        for (int dd = 0; dd < 16; ++dd) {
            const float4 fd = *reinterpret_cast<const float4*>(&fs[dg * 16 + dd][i4 * 4]);
            acc[dd] += fc.x * fd.x + fc.y * fd.y + fc.z * fd.z + fc.w * fd.w;
        }
    }
    size_t base = ((size_t)(b * 8 + blockIdx.x)) * 4096 + c * 64 + dg * 16;
    for (int dd = 0; dd < 16; ++dd)
        EPART[base + dd] = acc[dd];
}

__global__ __launch_bounds__(64) void k_cam_softmax(const float* __restrict__ EPART,
        float* __restrict__ attn) {
    __shared__ float e[4096];
    int b = blockIdx.x, t = threadIdx.x;
    for (int idx = t; idx < 4096; idx += 64) {
        float s = 0.f;
        for (int ch = 0; ch < 8; ++ch) s += EPART[((size_t)(b * 8 + ch)) * 4096 + idx];
        e[idx] = s;
    }
    __syncthreads();
    float mn = INFINITY;
    for (int d = 0; d < 64; ++d) mn = fminf(mn, e[t * 64 + d]);
    float s = 0.f;
    float* a = attn + (size_t)b * 4096 + t * 64;
    for (int d = 0; d < 64; ++d) { float p = __expf(mn - e[t * 64 + d]); a[d] = p; s += p; }
    float inv = 1.f / s;
    for (int d = 0; d < 64; ++d) a[d] *= inv;
}

// ---- CAM apply: scf = gamma*attn@f + f, written transposed bf16 ----
__global__ __launch_bounds__(256) void k_cam_apply(const float* __restrict__ attn,
        const float* __restrict__ f, const float* __restrict__ gamma,
        unsigned short* __restrict__ SCFT) {
    __shared__ __align__(16) float as[64 * 64];
    __shared__ unsigned short tile[128 * 66];
    int b = blockIdx.y;
    int l0 = blockIdx.x * 128;
    int t = threadIdx.x;
    int lq = t & 127, ch = t >> 7;
    for (int i = t; i < 4096; i += 256) as[i] = attn[(size_t)b * 4096 + i];
    __syncthreads();
    float acc[32];
#pragma unroll
    for (int i = 0; i < 32; ++i) acc[i] = 0.f;
    const float* fb = f + (size_t)b * IC * LP + l0 + lq;
    for (int d4 = 0; d4 < 16; ++d4) {
        float f0 = fb[(size_t)(4 * d4 + 0) * LP];
        float f1v = fb[(size_t)(4 * d4 + 1) * LP];
        float f2v = fb[(size_t)(4 * d4 + 2) * LP];
        float f3v = fb[(size_t)(4 * d4 + 3) * LP];
#pragma unroll
        for (int cc = 0; cc < 32; ++cc) {
            const float4 a4 = *reinterpret_cast<const float4*>(as + (ch * 32 + cc) * 64 + d4 * 4);
            acc[cc] += a4.x * f0 + a4.y * f1v + a4.z * f2v + a4.w * f3v;
        }
    }
    float gm = gamma[0];
#pragma unroll
    for (int cc = 0; cc < 32; ++cc) {
        float val = fmaf(gm, acc[cc], fb[(size_t)(ch * 32 + cc) * LP]);
        tile[lq * 66 + ch * 32 + cc] = f2bf(val);
    }
    __syncthreads();
    int li = t >> 1, half = t & 1;
    unsigned int* dst = (unsigned int*)(SCFT + ((size_t)(b * LP + l0 + li)) * IC + half * 32);
#pragma unroll
    for (int i = 0; i < 16; ++i)
        dst[i] = *(unsigned int*)(tile + li * 66 + half * 32 + 2 * i);
}

// ---- conv3 via 3 shifted K=64 MFMA GEMMs ----
__global__ __launch_bounds__(256) void k_conv3_mfma(const unsigned short* __restrict__ FTsrc,
        const unsigned short* __restrict__ WT, float* __restrict__ dst) {
    int lt = blockIdx.x, b = blockIdx.y;
    int l0 = lt * 64;
    int w = threadIdx.x >> 6, lane = threadIdx.x & 63, n = lane & 15, quad = lane >> 4;
    int lrow = l0 + w * 16 + n;
    f32x4 acc[4];
#pragma unroll
    for (int ot = 0; ot < 4; ++ot) acc[ot] = (f32x4){0.f, 0.f, 0.f, 0.f};
#pragma unroll
    for (int t3 = 0; t3 < 3; ++t3) {
        int row = lrow + t3 - 1;
        bshort8 fb[2];
#pragma unroll
        for (int kt = 0; kt < 2; ++kt) {
            if (row >= 0 && row < LP)
                fb[kt] = *(const bshort8*)(FTsrc + ((size_t)(b * LP + row)) * IC + kt * 32 + quad * 8);
            else fb[kt] = (bshort8){};
        }
#pragma unroll
        for (int ot = 0; ot < 4; ++ot)
#pragma unroll
            for (int kt = 0; kt < 2; ++kt) {
                bshort8 wf = *(const bshort8*)(WT + ((size_t)(t3 * 64 + ot * 16 + n)) * IC + kt * 32 + quad * 8);
                acc[ot] = __builtin_amdgcn_mfma_f32_16x16x32_bf16(wf, fb[kt], acc[ot], 0, 0, 0);
            }
    }
#pragma unroll
    for (int ot = 0; ot < 4; ++ot)
#pragma unroll
        for (int r = 0; r < 4; ++r) {
            int o = ot * 16 + quad * 4 + r;
            dst[((size_t)(b * IC + o)) * LP + lrow] = acc[ot][r];
        }
}

// ---- stage-2 BN+ReLU: outputs transposed bf16 + per-tile channel sums ----
__global__ __launch_bounds__(256) void k_bnrelu_t2(const float* __restrict__ fA,
        const float* __restrict__ fB, const float* __restrict__ stats,
        const float* __restrict__ gA, const float* __restrict__ bA,
        const float* __restrict__ gB, const float* __restrict__ bB,
        unsigned short* __restrict__ SACT, unsigned short* __restrict__ SCCT,
        float* __restrict__ FSPART) {
    __shared__ unsigned short tsA[64 * 66];
    __shared__ unsigned short tsB[64 * 66];
    int lt = blockIdx.x, b = blockIdx.y;
    int l0 = lt * 64;
    int t = threadIdx.x, lq = t & 63, cg = t >> 6;
    const float invN = 1.f / (float)(B * LP);
#pragma unroll
    for (int ci = 0; ci < 16; ++ci) {
        int c = cg * 16 + ci;
        float mu = stats[c * 2] * invN, va = stats[c * 2 + 1] * invN - mu * mu;
        float Aa = gA[c] * rsqrtf(va + BN_EPS), Ba = bA[c] - mu * Aa;
        float mb = stats[128 + c * 2] * invN, vv = stats[128 + c * 2 + 1] * invN - mb * mb;
        float Ab = gB[c] * rsqrtf(vv + BN_EPS), Bb = bB[c] - mb * Ab;
        size_t idx = ((size_t)(b * IC + c)) * LP + l0 + lq;
        float v1 = fmaf(Aa, fA[idx], Ba); v1 = v1 > 0.f ? v1 : 0.f;
        float v2 = fmaf(Ab, fB[idx], Bb); v2 = v2 > 0.f ? v2 : 0.f;
        tsA[lq * 66 + c] = f2bf(v1);
        tsB[lq * 66 + c] = f2bf(v2);
        float sum = v1 + v2;
#pragma unroll
        for (int off = 32; off; off >>= 1) sum += __shfl_down(sum, off, 64);
        if (lq == 0) FSPART[((size_t)(b * 32 + lt)) * 64 + c] = sum;
    }
    __syncthreads();
    int li = t >> 2, cc = t & 3;
    unsigned int* dA = (unsigned int*)(SACT + ((size_t)(b * LP + l0 + li)) * IC + cc * 16);
    unsigned int* dB = (unsigned int*)(SCCT + ((size_t)(b * LP + l0 + li)) * IC + cc * 16);
#pragma unroll
    for (int i = 0; i < 8; ++i) {
        dA[i] = *(unsigned int*)(tsA + li * 66 + cc * 16 + 2 * i);
        dB[i] = *(unsigned int*)(tsB + li * 66 + cc * 16 + 2 * i);
    }
}

// ---- final conv1x1 pair via MFMA ----
__global__ __launch_bounds__(256) void k_final_mfma(const unsigned short* __restrict__ SACT,
        const unsigned short* __restrict__ SCCT, const unsigned short* __restrict__ W67,
        const float* __restrict__ b6, const float* __restrict__ b7,
        float* __restrict__ out_sa, float* __restrict__ out_sc) {
    int lt = blockIdx.x, og = blockIdx.y, b = blockIdx.z;
    int l0 = lt * 64;
    int w = threadIdx.x >> 6, lane = threadIdx.x & 63, n = lane & 15, quad = lane >> 4;
    int lrow = l0 + w * 16 + n;
    bshort8 ba[2], bb[2];
#pragma unroll
    for (int kt = 0; kt < 2; ++kt) {
        ba[kt] = *(const bshort8*)(SACT + ((size_t)(b * LP + lrow)) * IC + kt * 32 + quad * 8);
        bb[kt] = *(const bshort8*)(SCCT + ((size_t)(b * LP + lrow)) * IC + kt * 32 + quad * 8);
    }
    f32x4 accA[4], accB[4];
#pragma unroll
    for (int ot = 0; ot < 4; ++ot) {
        accA[ot] = (f32x4){0.f, 0.f, 0.f, 0.f};
        accB[ot] = (f32x4){0.f, 0.f, 0.f, 0.f};
    }
#pragma unroll
    for (int ot = 0; ot < 4; ++ot)
#pragma unroll
        for (int kt = 0; kt < 2; ++kt) {
            bshort8 wa = *(const bshort8*)(W67 + (size_t)(og * 64 + ot * 16 + n) * IC + kt * 32 + quad * 8);
            bshort8 wb = *(const bshort8*)(W67 + 8192 + (size_t)(og * 64 + ot * 16 + n) * IC + kt * 32 + quad * 8);
            accA[ot] = __builtin_amdgcn_mfma_f32_16x16x32_bf16(wa, ba[kt], accA[ot], 0, 0, 0);
            accB[ot] = __builtin_amdgcn_mfma_f32_16x16x32_bf16(wb, bb[kt], accB[ot], 0, 0, 0);
        }
#pragma unroll
    for (int ot = 0; ot < 4; ++ot)
#pragma unroll
        for (int r = 0; r < 4; ++r) {
            int o = og * 64 + ot * 16 + quad * 4 + r;
            out_sa[((size_t)(b * OC + o)) * LP + lrow] = accA[ot][r] + b6[o];
            out_sc[((size_t)(b * OC + o)) * LP + lrow] = accB[ot][r] + b7[o];
        }
}

// ---- sasc = W8 @ mean(sa_conv+sc_conv) + b8 ----
__global__ __launch_bounds__(128) void k_sasc(const float* __restrict__ FSPART,
        const float* __restrict__ W8, const float* __restrict__ b8,
        float* __restrict__ out) {
    __shared__ float mean[64];
    int b = blockIdx.x, t = threadIdx.x;
    if (t < 64) {
        float s = 0.f;
        for (int lt = 0; lt < 32; ++lt) s += FSPART[((size_t)(b * 32 + lt)) * 64 + t];
        mean[t] = s * (1.f / (float)LP);
    }
    __syncthreads();
    float s = b8[t];
    for (int c = 0; c < 64; ++c) s = fmaf(W8[t * 64 + c], mean[c], s);
    out[b * OC + t] = s;
}

extern "C" void kernel_launch(void* const* d_in, const int* in_sizes, int n_in,
                              void* d_out, int out_size, void* d_ws, size_t ws_size,
                              hipStream_t stream) {
    (void)in_sizes; (void)n_in; (void)out_size; (void)ws_size;
    const float* x    = (const float*)d_in[0];
    const float* W5a  = (const float*)d_in[1];
    const float* g5a  = (const float*)d_in[2];
    const float* b5a  = (const float*)d_in[3];
    const float* W5c  = (const float*)d_in[4];
    const float* g5c  = (const float*)d_in[5];
    const float* b5c  = (const float*)d_in[6];
    const float* Wq   = (const float*)d_in[7];
    const float* bq   = (const float*)d_in[8];
    const float* Wk   = (const float*)d_in[9];
    const float* bk   = (const float*)d_in[10];
    const float* Wv   = (const float*)d_in[11];
    const float* bv   = (const float*)d_in[12];
    const float* gpam = (const float*)d_in[13];
    const float* gcam = (const float*)d_in[14];
    const float* W51  = (const float*)d_in[15];
    const float* g51  = (const float*)d_in[16];
    const float* b51  = (const float*)d_in[17];
    const float* W52  = (const float*)d_in[18];
    const float* g52  = (const float*)d_in[19];
    const float* b52  = (const float*)d_in[20];
    const float* W6   = (const float*)d_in[21];
    const float* b6   = (const float*)d_in[22];
    const float* W7   = (const float*)d_in[23];
    const float* b7   = (const float*)d_in[24];
    const float* W8   = (const float*)d_in[25];
    const float* b8   = (const float*)d_in[26];

    float* ws = (float*)d_ws;
    float* out = (float*)d_out;
    float* bufA = ws + OFF_A;
    float* bufB = ws + OFF_B;
    unsigned short* FT1  = (unsigned short*)(ws + OFF_FT1);
    unsigned short* SAFT = (unsigned short*)(ws + OFF_SAFT);
    unsigned short* SCFT = (unsigned short*)(ws + OFF_SCFT);
    unsigned short* SACT = (unsigned short*)(ws + OFF_SACT);
    unsigned short* SCCT = (unsigned short*)(ws + OFF_SCCT);
    unsigned short* VB   = (unsigned short*)(ws + OFF_VB);
    unsigned short* QT   = (unsigned short*)(ws + OFF_QT);
    unsigned short* KT   = (unsigned short*)(ws + OFF_KT);
    float* EPART  = ws + OFF_EPART;
    float* ATTN   = ws + OFF_ATTN;
    float* STATS  = ws + OFF_STATS;
    float* MLPART = ws + OFF_MLPART;
    float* FSPART = ws + OFF_FSPART;
    unsigned short* W5BF = (unsigned short*)(ws + OFF_W5BF);
    unsigned short* W67  = (unsigned short*)(ws + OFF_W67);
    unsigned short* WT   = (unsigned short*)(ws + OFF_WT);
    unsigned short* WQKV = (unsigned short*)(ws + OFF_WQKV);
    float* BQKV = ws + OFF_BQKV;

    float* out_sa = out + B * OC;
    float* out_sc = out + B * OC + (size_t)B * OC * LP;
    // out_sa region doubles as scratch: first XT (bf16), later OPART (bf16)
    unsigned short* XT    = (unsigned short*)out_sa;
    unsigned short* OPART = (unsigned short*)out_sa;

    k_wprep<<<309, 256, 0, stream>>>(W5a, W5c, W6, W7, W51, W52, Wq, Wk, Wv,
                                     bq, bk, bv, W5BF, W67, WT, WQKV, BQKV);
    k_xt<<<dim3(32, 4, B), 256, 0, stream>>>(x, XT);
    k_convx<<<dim3(32, 2, B), 256, 0, stream>>>(XT, W5BF, bufA, bufB);
    k_stats<<<128, 256, 0, stream>>>(bufA, bufB, STATS, STATS + 128);
    k_bnrelu_t1<<<dim3(32, B), 256, 0, stream>>>(bufA, bufB, STATS, g5a, b5a, g5c, b5c, FT1);
    k_qkv_mfma<<<dim3(32, B), 256, 0, stream>>>(FT1, WQKV, BQKV, QT, KT, VB);
    k_pam_mfma<<<dim3(32, 4, B), 256, 0, stream>>>(QT, KT, VB, OPART, MLPART);
    k_pam_combine<<<dim3(32, B), 256, 0, stream>>>(OPART, MLPART, bufA, gpam, SAFT);
    k_gram<<<dim3(8, B), 256, 0, stream>>>(bufB, EPART);
    k_cam_softmax<<<B, 64, 0, stream>>>(EPART, ATTN);
    k_cam_apply<<<dim3(16, B), 256, 0, stream>>>(ATTN, bufB, gcam, SCFT);
    k_conv3_mfma<<<dim3(32, B), 256, 0, stream>>>(SAFT, WT, bufA);
    k_conv3_mfma<<<dim3(32, B), 256, 0, stream>>>(SCFT, WT + 12288, bufB);
    k_stats<<<128, 256, 0, stream>>>(bufA, bufB, STATS + 256, STATS + 384);
    k_bnrelu_t2<<<dim3(32, B), 256, 0, stream>>>(bufA, bufB, STATS + 256, g51, b51,
                                                 g52, b52, SACT, SCCT, FSPART);
    k_final_mfma<<<dim3(32, 2, B), 256, 0, stream>>>(SACT, SCCT, W67, b6, b7, out_sa, out_sc);
    k_sasc<<<B, 128, 0, stream>>>(FSPART, W8, b8, out);
}

// Round 4
// 243.399 us; speedup vs baseline: 3.0340x; 1.3126x over previous
//
#include <hip/hip_runtime.h>
#include <math.h>

#define B 8
#define C 256
#define L 2046
#define LP 2048
#define IC 64
#define OC 128
#define BN_EPS 1e-5f
#define INVN (1.f / 16384.f)   // 1/(B*LP)

// ws offsets (float units)
#define OFF_Y1T    0u          // conv1 out (pre-BN) bf16 [b][l][64]
#define OFF_Y2C    524288u     // conv1 out (pre-BN) bf16 [b][64][l]
#define OFF_SAFT   1048576u    // sa_feat bf16 [b][l][64]
#define OFF_SCFT   1572864u    // sc_feat bf16 [b][l][64]
#define OFF_Y51T   2097152u    // conv3 out (pre-BN) bf16 [b][l][64]
#define OFF_Y52T   2621440u
#define OFF_VB     3145728u    // v bf16 [b][64][l]
#define OFF_QT     3670016u    // q bf16 [b][l][8]
#define OFF_KT     3735552u
#define OFF_LPART  3801088u    // pam denominators [b][32][4][64]
#define OFF_EPART  3866624u    // CAM gram partials [b][16][64][64]
#define OFF_ATTN   4390912u
#define OFF_PART1  4423680u    // stats partials [256 slots][256 blk]
#define OFF_PART2  4489216u
#define OFF_COEF1  4554752u    // (A,B) per channel [128][2]
#define OFF_COEF2  4555008u
#define OFF_FSUM   4555264u    // [b][64] atomic
#define OFF_W5BF   4555776u    // bf16 [128][256]
#define OFF_W67    4572160u    // bf16 [2][128][64]
#define OFF_WT     4580352u    // bf16 [2][3][64][64]
#define OFF_WQKV   4592640u    // bf16 [80][64]
#define OFF_BQKV   4595200u    // fp32 [80]

typedef __attribute__((ext_vector_type(8))) short bshort8;
typedef __attribute__((ext_vector_type(4))) float f32x4;

__device__ __forceinline__ unsigned short f2bf(float f) {
    union { float f; unsigned int u; } v; v.f = f;
    unsigned int r = v.u + 0x7fffu + ((v.u >> 16) & 1u);
    return (unsigned short)(r >> 16);
}
__device__ __forceinline__ float bf2f(unsigned short u) {
    union { unsigned int i; float f; } v; v.i = ((unsigned int)u) << 16;
    return v.f;
}
__device__ __forceinline__ unsigned int pk2(float a, float b) {
    return (unsigned int)f2bf(a) | ((unsigned int)f2bf(b) << 16);
}

// ---- weight prep + FSUM zero ----
__global__ __launch_bounds__(256) void k_wprep(
        const float* __restrict__ W5a, const float* __restrict__ W5c,
        const float* __restrict__ W6, const float* __restrict__ W7,
        const float* __restrict__ W51, const float* __restrict__ W52,
        const float* __restrict__ Wq, const float* __restrict__ Wk,
        const float* __restrict__ Wv, const float* __restrict__ bq,
        const float* __restrict__ bk, const float* __restrict__ bv,
        unsigned short* __restrict__ W5BF, unsigned short* __restrict__ W67,
        unsigned short* __restrict__ WT, unsigned short* __restrict__ WQKV,
        float* __restrict__ BQKV, float* __restrict__ FSUM) {
    int i = blockIdx.x * 256 + threadIdx.x;
    if (i < 32768) {
        int o = i >> 8, c = i & 255;
        W5BF[i] = f2bf(o < 64 ? W5a[o * 256 + c] : W5c[(o - 64) * 256 + c]);
    } else if (i < 49152) {
        int j = i - 32768; int g = j >> 13; int r = j & 8191;
        W67[j] = f2bf(g ? W7[r] : W6[r]);
    } else if (i < 73728) {
        int j = i - 49152;
        int c = j & 63, o = (j >> 6) & 63, wt = j >> 12; int w = wt / 3, t = wt % 3;
        const float* Ws = w ? W52 : W51;
        WT[j] = f2bf(Ws[(o * 64 + c) * 3 + t]);
    } else if (i < 78848) {
        int j = i - 73728; int o = j >> 6, c = j & 63;
        float v = o < 8 ? Wq[o * 64 + c] : (o < 16 ? Wk[(o - 8) * 64 + c] : Wv[(o - 16) * 64 + c]);
        WQKV[j] = f2bf(v);
    } else if (i < 78928) {
        int o = i - 78848;
        BQKV[o] = o < 8 ? bq[o] : (o < 16 ? bk[o - 8] : bv[o - 16]);
    } else if (i < 79440) {
        FSUM[i - 78928] = 0.f;
    }
}

// ---- conv1x1(x) via MFMA, direct x loads; writes pre-BN bf16 + stats partials ----
// grid (32, 2, B); og=0 -> Y1T [l][c], og=1 -> Y2C [c][l]
__global__ __launch_bounds__(256) void k_conv1(const float* __restrict__ x,
        const unsigned short* __restrict__ W5BF,
        unsigned short* __restrict__ Y1T, unsigned short* __restrict__ Y2C,
        float* __restrict__ PART1) {
    __shared__ float lds_part[4][128];
    int lt = blockIdx.x, og = blockIdx.y, b = blockIdx.z;
    int w = threadIdx.x >> 6, lane = threadIdx.x & 63;
    int n = lane & 15, quad = lane >> 4;
    int lp = lt * 64 + w * 16 + n;          // padded output row
    int ls = lp - 1;                        // source col in x
    bool valid = (ls >= 0) && (ls < L);
    f32x4 acc[4];
#pragma unroll
    for (int ot = 0; ot < 4; ++ot) acc[ot] = (f32x4){0.f, 0.f, 0.f, 0.f};
    for (int ck = 0; ck < 8; ++ck) {
        int c0 = ck * 32 + quad * 8;
        bshort8 xb = {};
        if (valid) {
            const float* xs = x + ((size_t)(b * C + c0)) * L + ls;
#pragma unroll
            for (int j = 0; j < 8; ++j)
                ((unsigned short*)&xb)[j] = f2bf(xs[(size_t)j * L]);
        }
#pragma unroll
        for (int ot = 0; ot < 4; ++ot) {
            bshort8 wf = *(const bshort8*)(W5BF + (size_t)(og * 64 + ot * 16 + n) * C + ck * 32 + quad * 8);
            acc[ot] = __builtin_amdgcn_mfma_f32_16x16x32_bf16(wf, xb, acc[ot], 0, 0, 0);
        }
    }
    // store
    if (og == 0) {
#pragma unroll
        for (int ot = 0; ot < 4; ++ot) {
            uint2 pv;
            pv.x = pk2(acc[ot][0], acc[ot][1]);
            pv.y = pk2(acc[ot][2], acc[ot][3]);
            *(uint2*)(Y1T + ((size_t)(b * LP + lp)) * IC + ot * 16 + quad * 4) = pv;
        }
    } else {
#pragma unroll
        for (int ot = 0; ot < 4; ++ot)
#pragma unroll
            for (int r = 0; r < 4; ++r) {
                int o = ot * 16 + quad * 4 + r;
                Y2C[((size_t)(b * IC + o)) * LP + lp] = f2bf(acc[ot][r]);
            }
    }
    // stats partials (sum, sumsq per channel over this block's 64 l)
#pragma unroll
    for (int ot = 0; ot < 4; ++ot)
#pragma unroll
        for (int r = 0; r < 4; ++r) {
            float s = acc[ot][r], q = s * s;
#pragma unroll
            for (int msk = 1; msk < 16; msk <<= 1) {
                s += __shfl_xor(s, msk, 64);
                q += __shfl_xor(q, msk, 64);
            }
            if (n == 0) {
                int ch = ot * 16 + quad * 4 + r;
                lds_part[w][ch * 2] = s;
                lds_part[w][ch * 2 + 1] = q;
            }
        }
    __syncthreads();
    int t = threadIdx.x;
    if (t < 128) {
        float s = lds_part[0][t] + lds_part[1][t] + lds_part[2][t] + lds_part[3][t];
        PART1[(size_t)(og * 128 + t) * 256 + (b * 32 + lt)] = s;
    }
}

// ---- reduce stats partials -> BN affine coefs (A, B) per channel ----
__global__ __launch_bounds__(256) void k_red(const float* __restrict__ PART,
        const float* __restrict__ g0, const float* __restrict__ b0,
        const float* __restrict__ g1, const float* __restrict__ b1,
        float* __restrict__ COEF) {
    int ch = blockIdx.x;   // 0..127
    int t = threadIdx.x;
    float s = PART[(size_t)(ch * 2) * 256 + t];
    float q = PART[(size_t)(ch * 2 + 1) * 256 + t];
    for (int off = 32; off; off >>= 1) {
        s += __shfl_down(s, off, 64);
        q += __shfl_down(q, off, 64);
    }
    __shared__ float rs[4], rq[4];
    if ((t & 63) == 0) { rs[t >> 6] = s; rq[t >> 6] = q; }
    __syncthreads();
    if (t == 0) {
        float S = rs[0] + rs[1] + rs[2] + rs[3];
        float Q = rq[0] + rq[1] + rq[2] + rq[3];
        float mu = S * INVN;
        float var = Q * INVN - mu * mu;
        float gv = ch < 64 ? g0[ch] : g1[ch - 64];
        float bv = ch < 64 ? b0[ch] : b1[ch - 64];
        float A = gv * rsqrtf(var + BN_EPS);
        COEF[ch * 2] = A;
        COEF[ch * 2 + 1] = bv - mu * A;
    }
}

// ---- qkv via MFMA with BN-on-the-fly from Y1T ----
__global__ __launch_bounds__(256) void k_qkv(const unsigned short* __restrict__ Y1T,
        const float* __restrict__ COEF1,
        const unsigned short* __restrict__ WQKV, const float* __restrict__ BQKV,
        unsigned short* __restrict__ QT, unsigned short* __restrict__ KT,
        unsigned short* __restrict__ VB) {
    __shared__ float cA[64], cB[64];
    int lt = blockIdx.x, b = blockIdx.y;
    int t = threadIdx.x;
    if (t < 64) { cA[t] = COEF1[t * 2]; cB[t] = COEF1[t * 2 + 1]; }
    __syncthreads();
    int w = t >> 6, lane = t & 63, n = lane & 15, quad = lane >> 4;
    int lrow = lt * 64 + w * 16 + n;
    bshort8 fb[2];
#pragma unroll
    for (int kt = 0; kt < 2; ++kt) {
        bshort8 raw = *(const bshort8*)(Y1T + ((size_t)(b * LP + lrow)) * IC + kt * 32 + quad * 8);
        bshort8 f;
#pragma unroll
        for (int j = 0; j < 8; ++j) {
            int c = kt * 32 + quad * 8 + j;
            float v = fmaf(cA[c], bf2f((unsigned short)raw[j]), cB[c]);
            v = fmaxf(v, 0.f);
            ((unsigned short*)&f)[j] = f2bf(v);
        }
        fb[kt] = f;
    }
    f32x4 acc[5];
#pragma unroll
    for (int ot = 0; ot < 5; ++ot) {
        f32x4 a = {0.f, 0.f, 0.f, 0.f};
#pragma unroll
        for (int kt = 0; kt < 2; ++kt) {
            bshort8 wf = *(const bshort8*)(WQKV + (size_t)(ot * 16 + n) * IC + kt * 32 + quad * 8);
            a = __builtin_amdgcn_mfma_f32_16x16x32_bf16(wf, fb[kt], a, 0, 0, 0);
        }
        acc[ot] = a;
    }
#pragma unroll
    for (int ot = 0; ot < 5; ++ot)
#pragma unroll
        for (int r = 0; r < 4; ++r) {
            int o = ot * 16 + quad * 4 + r;
            unsigned short bv16 = f2bf(acc[ot][r] + BQKV[o]);
            if (ot == 0) {
                if (o < 8) QT[((size_t)(b * LP + lrow)) * 8 + o] = bv16;
                else KT[((size_t)(b * LP + lrow)) * 8 + (o - 8)] = bv16;
            } else {
                VB[((size_t)(b * IC + (o - 16))) * LP + lrow] = bv16;
            }
        }
}

// ---- flash PAM without max-tracking (scores provably small); split-K x4 ----
__global__ __launch_bounds__(256) void k_pam(
        const unsigned short* __restrict__ qT, const unsigned short* __restrict__ kT,
        const unsigned short* __restrict__ vb,
        unsigned short* __restrict__ OPART, float* __restrict__ LPART) {
    __shared__ unsigned char smem[18432];
    unsigned short* vs = (unsigned short*)smem;       // [64][72]
    unsigned short* ps = vs + 4608;                   // 4 x [16][72]
    float* os = (float*)smem;                         // [64][65] aliased after loop
    int qt = blockIdx.x, ks = blockIdx.y, b = blockIdx.z;
    int l0 = qt * 64;
    int tid = threadIdx.x;
    int wq = tid >> 6, lane = tid & 63, n = lane & 15, quad = lane >> 4;
    bshort8 qa = {};
    if (quad == 0)
        qa = *(const bshort8*)(qT + ((size_t)(b * LP + l0 + wq * 16 + n)) * 8);
    f32x4 acc[4];
#pragma unroll
    for (int s = 0; s < 4; ++s) acc[s] = (f32x4){0.f, 0.f, 0.f, 0.f};
    float li[4] = {0.f, 0.f, 0.f, 0.f};
    unsigned short* pw = ps + wq * 16 * 72;

    for (int it = 0; it < 8; ++it) {
        int m0 = ks * 512 + it * 64;
        __syncthreads();
        {
            int row = tid >> 2, chn = tid & 3;
            const unsigned short* src = vb + ((size_t)(b * IC + row)) * LP + m0 + chn * 16;
            unsigned short* dstl = vs + row * 72 + chn * 16;
            *(bshort8*)dstl = *(const bshort8*)src;
            *(bshort8*)(dstl + 8) = *(const bshort8*)(src + 8);
        }
        bshort8 kb[4];
#pragma unroll
        for (int s = 0; s < 4; ++s) kb[s] = (bshort8){};
        if (quad == 0) {
#pragma unroll
            for (int s = 0; s < 4; ++s)
                kb[s] = *(const bshort8*)(kT + ((size_t)(b * LP + m0 + s * 16 + n)) * 8);
        }
        __syncthreads();
        f32x4 sc[4];
#pragma unroll
        for (int s = 0; s < 4; ++s)
            sc[s] = __builtin_amdgcn_mfma_f32_16x16x32_bf16(qa, kb[s],
                        (f32x4){0.f, 0.f, 0.f, 0.f}, 0, 0, 0);
#pragma unroll
        for (int s = 0; s < 4; ++s)
#pragma unroll
            for (int r = 0; r < 4; ++r) {
                float p = __expf(sc[s][r]);
                li[r] += p;
                pw[(quad * 4 + r) * 72 + s * 16 + n] = f2bf(p);
            }
#pragma unroll
        for (int step = 0; step < 2; ++step) {
            bshort8 pa = *(const bshort8*)(pw + n * 72 + step * 32 + quad * 8);
#pragma unroll
            for (int s = 0; s < 4; ++s) {
                bshort8 vf = *(const bshort8*)(vs + (s * 16 + n) * 72 + step * 32 + quad * 8);
                acc[s] = __builtin_amdgcn_mfma_f32_16x16x32_bf16(pa, vf, acc[s], 0, 0, 0);
            }
        }
    }
    __syncthreads();
#pragma unroll
    for (int s = 0; s < 4; ++s)
#pragma unroll
        for (int r = 0; r < 4; ++r)
            os[(s * 16 + n) * 65 + wq * 16 + quad * 4 + r] = acc[s][r];
    size_t lbase = ((size_t)((b * 32 + qt) * 4 + ks)) * 64;
#pragma unroll
    for (int r = 0; r < 4; ++r) {
        float s_ = li[r];
#pragma unroll
        for (int msk = 1; msk < 16; msk <<= 1) s_ += __shfl_xor(s_, msk, 64);
        if (n == 0) LPART[lbase + wq * 16 + quad * 4 + r] = s_;
    }
    __syncthreads();
    size_t ob = ((size_t)((b * 32 + qt) * 4 + ks)) * 4096;
    int c = tid >> 2, qc = tid & 3;
    unsigned int* od = (unsigned int*)(OPART + ob + c * 64 + qc * 16);
#pragma unroll
    for (int i = 0; i < 8; ++i)
        od[i] = pk2(os[c * 65 + qc * 16 + 2 * i], os[c * 65 + qc * 16 + 2 * i + 1]);
}

// ---- merge split-K (linear), add BN'd residual, write sa_feat^T bf16 ----
__global__ __launch_bounds__(256) void k_pam_combine(
        const unsigned short* __restrict__ OPART, const float* __restrict__ LPART,
        const unsigned short* __restrict__ Y1T, const float* __restrict__ COEF1,
        const float* __restrict__ gamma, unsigned short* __restrict__ SAFT) {
    __shared__ float dn[64];
    __shared__ float cA[64], cB[64];
    __shared__ unsigned short tile[64 * 66];
    int qt = blockIdx.x, b = blockIdx.y;
    int l0 = qt * 64;
    int t = threadIdx.x;
    if (t < 64) {
        cA[t] = COEF1[t * 2]; cB[t] = COEF1[t * 2 + 1];
        size_t lbase = ((size_t)((b * 32 + qt) * 4)) * 64;
        dn[t] = LPART[lbase + t] + LPART[lbase + 64 + t] +
                LPART[lbase + 128 + t] + LPART[lbase + 192 + t];
    }
    __syncthreads();
    int c = t >> 2, qc = t & 3;
    float O[16];
#pragma unroll
    for (int i = 0; i < 16; ++i) O[i] = 0.f;
    size_t ob = ((size_t)((b * 32 + qt) * 4)) * 4096 + c * 64 + qc * 16;
#pragma unroll
    for (int s = 0; s < 4; ++s) {
        bshort8 p0 = *(const bshort8*)(OPART + ob + (size_t)s * 4096);
        bshort8 p1 = *(const bshort8*)(OPART + ob + (size_t)s * 4096 + 8);
#pragma unroll
        for (int i = 0; i < 8; ++i) {
            O[i]     += bf2f((unsigned short)p0[i]);
            O[8 + i] += bf2f((unsigned short)p1[i]);
        }
    }
    float gm = gamma[0];
#pragma unroll
    for (int i = 0; i < 16; ++i) {
        int q = qc * 16 + i;
        unsigned short raw = Y1T[((size_t)(b * LP + l0 + q)) * IC + c];
        float f1v = fmaxf(fmaf(cA[c], bf2f(raw), cB[c]), 0.f);
        float val = fmaf(gm, O[i] / dn[q], f1v);
        tile[q * 66 + c] = f2bf(val);
    }
    __syncthreads();
    int li = t >> 2, cc = t & 3;
    unsigned int* dst = (unsigned int*)(SAFT + ((size_t)(b * LP + l0 + li)) * IC + cc * 16);
#pragma unroll
    for (int i = 0; i < 8; ++i)
        dst[i] = *(unsigned int*)(tile + li * 66 + cc * 16 + 2 * i);
}

// ---- CAM Gram partials from Y2C with BN-on-the-fly ----
__global__ __launch_bounds__(256) void k_gram(const unsigned short* __restrict__ Y2C,
        const float* __restrict__ COEF1, float* __restrict__ EPART) {
    __shared__ float fs[64][132];
    __shared__ float cA[64], cB[64];
    int b = blockIdx.y;
    int l0 = blockIdx.x * 128;
    int t = threadIdx.x;
    if (t < 64) { cA[t] = COEF1[(64 + t) * 2]; cB[t] = COEF1[(64 + t) * 2 + 1]; }
    __syncthreads();
    for (int i = t; i < 64 * 64; i += 256) {
        int c = i >> 6, i2 = i & 63;
        unsigned int u = *(const unsigned int*)(Y2C + ((size_t)(b * IC + c)) * LP + l0 + i2 * 2);
        float A = cA[c], Bc = cB[c];
        fs[c][i2 * 2]     = fmaxf(fmaf(A, bf2f((unsigned short)u), Bc), 0.f);
        fs[c][i2 * 2 + 1] = fmaxf(fmaf(A, bf2f((unsigned short)(u >> 16)), Bc), 0.f);
    }
    __syncthreads();
    int c = t >> 2, dg = t & 3;
    float acc[16];
#pragma unroll
    for (int i = 0; i < 16; ++i) acc[i] = 0.f;
    for (int i4 = 0; i4 < 32; ++i4) {
        const float4 fc = *reinterpret_cast<const float4*>(&fs[c][i4 * 4]);
#pragma unroll
        for (int dd = 0; dd < 16; ++dd) {
            const float4 fd = *reinterpret_cast<const float4*>(&fs[dg * 16 + dd][i4 * 4]);
            acc[dd] += fc.x * fd.x + fc.y * fd.y + fc.z * fd.z + fc.w * fd.w;
        }
    }
    size_t base = ((size_t)(b * 16 + blockIdx.x)) * 4096 + c * 64 + dg * 16;
    for (int dd = 0; dd < 16; ++dd)
        EPART[base + dd] = acc[dd];
}

__global__ __launch_bounds__(256) void k_cam_softmax(const float* __restrict__ EPART,
        float* __restrict__ attn) {
    __shared__ float e[4096];
    int b = blockIdx.x, t = threadIdx.x;
    for (int idx = t; idx < 4096; idx += 256) {
        float s = 0.f;
        for (int ch = 0; ch < 16; ++ch) s += EPART[((size_t)(b * 16 + ch)) * 4096 + idx];
        e[idx] = s;
    }
    __syncthreads();
    if (t < 64) {
        float mn = INFINITY;
        for (int d = 0; d < 64; ++d) mn = fminf(mn, e[t * 64 + d]);
        float s = 0.f;
        float* a = attn + (size_t)b * 4096 + t * 64;
        for (int d = 0; d < 64; ++d) { float p = __expf(mn - e[t * 64 + d]); a[d] = p; s += p; }
        float inv = 1.f / s;
        for (int d = 0; d < 64; ++d) a[d] *= inv;
    }
}

// ---- CAM apply with BN-on-the-fly; writes sc_feat^T bf16 ----
__global__ __launch_bounds__(256) void k_cam_apply(const float* __restrict__ attn,
        const unsigned short* __restrict__ Y2C, const float* __restrict__ COEF1,
        const float* __restrict__ gamma, unsigned short* __restrict__ SCFT) {
    __shared__ __align__(16) float as[64 * 64];
    __shared__ float cA[64], cB[64];
    __shared__ unsigned short tile[128 * 66];
    int b = blockIdx.y;
    int l0 = blockIdx.x * 128;
    int t = threadIdx.x;
    int lq = t & 127, ch = t >> 7;
    if (t < 64) { cA[t] = COEF1[(64 + t) * 2]; cB[t] = COEF1[(64 + t) * 2 + 1]; }
    for (int i = t; i < 4096; i += 256) as[i] = attn[(size_t)b * 4096 + i];
    __syncthreads();
    float acc[32];
#pragma unroll
    for (int i = 0; i < 32; ++i) acc[i] = 0.f;
    const unsigned short* fb = Y2C + (size_t)b * IC * LP + l0 + lq;
    for (int d4 = 0; d4 < 16; ++d4) {
        float fv[4];
#pragma unroll
        for (int i = 0; i < 4; ++i) {
            int d = 4 * d4 + i;
            fv[i] = fmaxf(fmaf(cA[d], bf2f(fb[(size_t)d * LP]), cB[d]), 0.f);
        }
#pragma unroll
        for (int cc = 0; cc < 32; ++cc) {
            const float4 a4 = *reinterpret_cast<const float4*>(as + (ch * 32 + cc) * 64 + d4 * 4);
            acc[cc] += a4.x * fv[0] + a4.y * fv[1] + a4.z * fv[2] + a4.w * fv[3];
        }
    }
    float gm = gamma[0];
#pragma unroll
    for (int cc = 0; cc < 32; ++cc) {
        int c = ch * 32 + cc;
        float res = fmaxf(fmaf(cA[c], bf2f(fb[(size_t)c * LP]), cB[c]), 0.f);
        tile[lq * 66 + c] = f2bf(fmaf(gm, acc[cc], res));
    }
    __syncthreads();
    int li = t >> 1, half = t & 1;
    unsigned int* dst = (unsigned int*)(SCFT + ((size_t)(b * LP + l0 + li)) * IC + half * 32);
#pragma unroll
    for (int i = 0; i < 16; ++i)
        dst[i] = *(unsigned int*)(tile + li * 66 + half * 32 + 2 * i);
}

// ---- conv3 (both branches, og picks) -> pre-BN bf16 + stats partials ----
__global__ __launch_bounds__(256) void k_conv3(const unsigned short* __restrict__ SAFT,
        const unsigned short* __restrict__ SCFT, const unsigned short* __restrict__ WTall,
        unsigned short* __restrict__ Y51T, unsigned short* __restrict__ Y52T,
        float* __restrict__ PART2) {
    __shared__ float lds_part[4][128];
    int lt = blockIdx.x, og = blockIdx.y, b = blockIdx.z;
    const unsigned short* FTsrc = og ? SCFT : SAFT;
    const unsigned short* WT = WTall + og * 12288;
    unsigned short* dst = og ? Y52T : Y51T;
    int l0 = lt * 64;
    int w = threadIdx.x >> 6, lane = threadIdx.x & 63, n = lane & 15, quad = lane >> 4;
    int lrow = l0 + w * 16 + n;
    f32x4 acc[4];
#pragma unroll
    for (int ot = 0; ot < 4; ++ot) acc[ot] = (f32x4){0.f, 0.f, 0.f, 0.f};
#pragma unroll
    for (int t3 = 0; t3 < 3; ++t3) {
        int row = lrow + t3 - 1;
        bshort8 fb[2];
#pragma unroll
        for (int kt = 0; kt < 2; ++kt) {
            if (row >= 0 && row < LP)
                fb[kt] = *(const bshort8*)(FTsrc + ((size_t)(b * LP + row)) * IC + kt * 32 + quad * 8);
            else fb[kt] = (bshort8){};
        }
#pragma unroll
        for (int ot = 0; ot < 4; ++ot)
#pragma unroll
            for (int kt = 0; kt < 2; ++kt) {
                bshort8 wf = *(const bshort8*)(WT + ((size_t)(t3 * 64 + ot * 16 + n)) * IC + kt * 32 + quad * 8);
                acc[ot] = __builtin_amdgcn_mfma_f32_16x16x32_bf16(wf, fb[kt], acc[ot], 0, 0, 0);
            }
    }
#pragma unroll
    for (int ot = 0; ot < 4; ++ot) {
        uint2 pv;
        pv.x = pk2(acc[ot][0], acc[ot][1]);
        pv.y = pk2(acc[ot][2], acc[ot][3]);
        *(uint2*)(dst + ((size_t)(b * LP + lrow)) * IC + ot * 16 + quad * 4) = pv;
    }
#pragma unroll
    for (int ot = 0; ot < 4; ++ot)
#pragma unroll
        for (int r = 0; r < 4; ++r) {
            float s = acc[ot][r], q = s * s;
#pragma unroll
            for (int msk = 1; msk < 16; msk <<= 1) {
                s += __shfl_xor(s, msk, 64);
                q += __shfl_xor(q, msk, 64);
            }
            if (n == 0) {
                int cch = ot * 16 + quad * 4 + r;
                lds_part[w][cch * 2] = s;
                lds_part[w][cch * 2 + 1] = q;
            }
        }
    __syncthreads();
    int t = threadIdx.x;
    if (t < 128) {
        float s = lds_part[0][t] + lds_part[1][t] + lds_part[2][t] + lds_part[3][t];
        PART2[(size_t)(og * 128 + t) * 256 + (b * 32 + lt)] = s;
    }
}

// ---- final conv1x1 pair, BN-on-the-fly inputs, + fused channel sums for sasc ----
__global__ __launch_bounds__(256) void k_final(const unsigned short* __restrict__ Y51T,
        const unsigned short* __restrict__ Y52T, const float* __restrict__ COEF2,
        const unsigned short* __restrict__ W67,
        const float* __restrict__ b6, const float* __restrict__ b7,
        float* __restrict__ out_sa, float* __restrict__ out_sc,
        float* __restrict__ FSUM) {
    __shared__ float cA[128], cB[128];
    __shared__ float fsw[4][64];
    int lt = blockIdx.x, og = blockIdx.y, b = blockIdx.z;
    int t = threadIdx.x;
    if (t < 128) { cA[t] = COEF2[t * 2]; cB[t] = COEF2[t * 2 + 1]; }
    __syncthreads();
    int w = t >> 6, lane = t & 63, n = lane & 15, quad = lane >> 4;
    int lrow = lt * 64 + w * 16 + n;
    float fs_lane[16];
    bshort8 ba[2], bb[2];
#pragma unroll
    for (int kt = 0; kt < 2; ++kt) {
        bshort8 ra = *(const bshort8*)(Y51T + ((size_t)(b * LP + lrow)) * IC + kt * 32 + quad * 8);
        bshort8 rb = *(const bshort8*)(Y52T + ((size_t)(b * LP + lrow)) * IC + kt * 32 + quad * 8);
        bshort8 fa, fb;
#pragma unroll
        for (int j = 0; j < 8; ++j) {
            int c = kt * 32 + quad * 8 + j;
            float v1 = fmaxf(fmaf(cA[c], bf2f((unsigned short)ra[j]), cB[c]), 0.f);
            float v2 = fmaxf(fmaf(cA[64 + c], bf2f((unsigned short)rb[j]), cB[64 + c]), 0.f);
            ((unsigned short*)&fa)[j] = f2bf(v1);
            ((unsigned short*)&fb)[j] = f2bf(v2);
            fs_lane[kt * 8 + j] = v1 + v2;
        }
        ba[kt] = fa; bb[kt] = fb;
    }
    f32x4 accA[4], accB[4];
#pragma unroll
    for (int ot = 0; ot < 4; ++ot) {
        accA[ot] = (f32x4){0.f, 0.f, 0.f, 0.f};
        accB[ot] = (f32x4){0.f, 0.f, 0.f, 0.f};
    }
#pragma unroll
    for (int ot = 0; ot < 4; ++ot)
#pragma unroll
        for (int kt = 0; kt < 2; ++kt) {
            bshort8 wa = *(const bshort8*)(W67 + (size_t)(og * 64 + ot * 16 + n) * IC + kt * 32 + quad * 8);
            bshort8 wb = *(const bshort8*)(W67 + 8192 + (size_t)(og * 64 + ot * 16 + n) * IC + kt * 32 + quad * 8);
            accA[ot] = __builtin_amdgcn_mfma_f32_16x16x32_bf16(wa, ba[kt], accA[ot], 0, 0, 0);
            accB[ot] = __builtin_amdgcn_mfma_f32_16x16x32_bf16(wb, bb[kt], accB[ot], 0, 0, 0);
        }
#pragma unroll
    for (int ot = 0; ot < 4; ++ot)
#pragma unroll
        for (int r = 0; r < 4; ++r) {
            int o = og * 64 + ot * 16 + quad * 4 + r;
            out_sa[((size_t)(b * OC + o)) * LP + lrow] = accA[ot][r] + b6[o];
            out_sc[((size_t)(b * OC + o)) * LP + lrow] = accB[ot][r] + b7[o];
        }
    if (og == 0) {
#pragma unroll
        for (int i = 0; i < 16; ++i) {
            float s = fs_lane[i];
#pragma unroll
            for (int msk = 1; msk < 16; msk <<= 1) s += __shfl_xor(s, msk, 64);
            if (n == 0) {
                int c = (i >> 3) * 32 + quad * 8 + (i & 7);
                fsw[w][c] = s;
            }
        }
        __syncthreads();
        if (t < 64)
            atomicAdd(&FSUM[b * 64 + t], fsw[0][t] + fsw[1][t] + fsw[2][t] + fsw[3][t]);
    }
}

// ---- sasc = W8 @ mean(sa_conv+sc_conv) + b8 ----
__global__ __launch_bounds__(128) void k_sasc(const float* __restrict__ FSUM,
        const float* __restrict__ W8, const float* __restrict__ b8,
        float* __restrict__ out) {
    __shared__ float mean[64];
    int b = blockIdx.x, t = threadIdx.x;
    if (t < 64) mean[t] = FSUM[b * 64 + t] * (1.f / (float)LP);
    __syncthreads();
    float s = b8[t];
    for (int c = 0; c < 64; ++c) s = fmaf(W8[t * 64 + c], mean[c], s);
    out[b * OC + t] = s;
}

extern "C" void kernel_launch(void* const* d_in, const int* in_sizes, int n_in,
                              void* d_out, int out_size, void* d_ws, size_t ws_size,
                              hipStream_t stream) {
    (void)in_sizes; (void)n_in; (void)out_size; (void)ws_size;
    const float* x    = (const float*)d_in[0];
    const float* W5a  = (const float*)d_in[1];
    const float* g5a  = (const float*)d_in[2];
    const float* b5a  = (const float*)d_in[3];
    const float* W5c  = (const float*)d_in[4];
    const float* g5c  = (const float*)d_in[5];
    const float* b5c  = (const float*)d_in[6];
    const float* Wq   = (const float*)d_in[7];
    const float* bq   = (const float*)d_in[8];
    const float* Wk   = (const float*)d_in[9];
    const float* bk   = (const float*)d_in[10];
    const float* Wv   = (const float*)d_in[11];
    const float* bv   = (const float*)d_in[12];
    const float* gpam = (const float*)d_in[13];
    const float* gcam = (const float*)d_in[14];
    const float* W51  = (const float*)d_in[15];
    const float* g51  = (const float*)d_in[16];
    const float* b51  = (const float*)d_in[17];
    const float* W52  = (const float*)d_in[18];
    const float* g52  = (const float*)d_in[19];
    const float* b52  = (const float*)d_in[20];
    const float* W6   = (const float*)d_in[21];
    const float* b6   = (const float*)d_in[22];
    const float* W7   = (const float*)d_in[23];
    const float* b7   = (const float*)d_in[24];
    const float* W8   = (const float*)d_in[25];
    const float* b8   = (const float*)d_in[26];

    float* ws = (float*)d_ws;
    float* out = (float*)d_out;
    unsigned short* Y1T  = (unsigned short*)(ws + OFF_Y1T);
    unsigned short* Y2C  = (unsigned short*)(ws + OFF_Y2C);
    unsigned short* SAFT = (unsigned short*)(ws + OFF_SAFT);
    unsigned short* SCFT = (unsigned short*)(ws + OFF_SCFT);
    unsigned short* Y51T = (unsigned short*)(ws + OFF_Y51T);
    unsigned short* Y52T = (unsigned short*)(ws + OFF_Y52T);
    unsigned short* VB   = (unsigned short*)(ws + OFF_VB);
    unsigned short* QT   = (unsigned short*)(ws + OFF_QT);
    unsigned short* KT   = (unsigned short*)(ws + OFF_KT);
    float* LPART  = ws + OFF_LPART;
    float* EPART  = ws + OFF_EPART;
    float* ATTN   = ws + OFF_ATTN;
    float* PART1  = ws + OFF_PART1;
    float* PART2  = ws + OFF_PART2;
    float* COEF1  = ws + OFF_COEF1;
    float* COEF2  = ws + OFF_COEF2;
    float* FSUM   = ws + OFF_FSUM;
    unsigned short* W5BF = (unsigned short*)(ws + OFF_W5BF);
    unsigned short* W67  = (unsigned short*)(ws + OFF_W67);
    unsigned short* WT   = (unsigned short*)(ws + OFF_WT);
    unsigned short* WQKV = (unsigned short*)(ws + OFF_WQKV);
    float* BQKV = ws + OFF_BQKV;

    float* out_sa = out + B * OC;
    float* out_sc = out + B * OC + (size_t)B * OC * LP;
    unsigned short* OPART = (unsigned short*)out_sa;  // scratch, overwritten by k_final

    k_wprep<<<311, 256, 0, stream>>>(W5a, W5c, W6, W7, W51, W52, Wq, Wk, Wv,
                                     bq, bk, bv, W5BF, W67, WT, WQKV, BQKV, FSUM);
    k_conv1<<<dim3(32, 2, B), 256, 0, stream>>>(x, W5BF, Y1T, Y2C, PART1);
    k_red<<<128, 256, 0, stream>>>(PART1, g5a, b5a, g5c, b5c, COEF1);
    k_qkv<<<dim3(32, B), 256, 0, stream>>>(Y1T, COEF1, WQKV, BQKV, QT, KT, VB);
    k_pam<<<dim3(32, 4, B), 256, 0, stream>>>(QT, KT, VB, OPART, LPART);
    k_pam_combine<<<dim3(32, B), 256, 0, stream>>>(OPART, LPART, Y1T, COEF1, gpam, SAFT);
    k_gram<<<dim3(16, B), 256, 0, stream>>>(Y2C, COEF1, EPART);
    k_cam_softmax<<<B, 256, 0, stream>>>(EPART, ATTN);
    k_cam_apply<<<dim3(16, B), 256, 0, stream>>>(ATTN, Y2C, COEF1, gcam, SCFT);
    k_conv3<<<dim3(32, 2, B), 256, 0, stream>>>(SAFT, SCFT, WT, Y51T, Y52T, PART2);
    k_red<<<128, 256, 0, stream>>>(PART2, g51, b51, g52, b52, COEF2);
    k_final<<<dim3(32, 2, B), 256, 0, stream>>>(Y51T, Y52T, COEF2, W67, b6, b7,
                                                out_sa, out_sc, FSUM);
    k_sasc<<<B, 128, 0, stream>>>(FSUM, W8, b8, out);
}